// Round 8
// baseline (624.170 us; speedup 1.0000x reference)
//
#include <hip/hip_runtime.h>

typedef unsigned short u16;
typedef unsigned int u32;

#define N_NODES 50000
#define N_EDGES 1600000
#define CH 128
#define CHW 64          // u32 words (or float2s) per 128-ch row
#define NG 512
#define CAP 128         // bucket capacity per node (Poisson(32): P(>=128) ~ 1e-43)
#define PAD 136         // LDS row stride in bf16 elems (272B: 16B-aligned, bank-balanced)

typedef __bf16 bf16x8 __attribute__((ext_vector_type(8)));
typedef float f32x4 __attribute__((ext_vector_type(4)));

__device__ __forceinline__ float bflo(u32 v) { return __builtin_bit_cast(float, v << 16); }
__device__ __forceinline__ float bfhi(u32 v) { return __builtin_bit_cast(float, v & 0xffff0000u); }
__device__ __forceinline__ float bf2f(u16 v) { return __builtin_bit_cast(float, ((u32)v) << 16); }
__device__ __forceinline__ u16 f2bf(float f) {
    u32 x = __builtin_bit_cast(u32, f);
    x += 0x7fffu + ((x >> 16) & 1u);   // RNE
    return (u16)(x >> 16);
}
__device__ __forceinline__ u32 pack2(float a, float b) {
    return (u32)f2bf(a) | ((u32)f2bf(b) << 16);
}
// wave-ballot probe: true if the 64 sampled u32 words look like packed bf16 pairs
__device__ __forceinline__ bool probe_bf16(u32 w0) {
    u32 ex = (w0 >> 7) & 0xFFu;
    bool ok = ((w0 & 0x7FFFu) == 0u) || (ex >= 0x70u && ex <= 0x8Fu);
    return __popcll(__ballot(ok)) >= 48;
}

// ---------------- bucket build ----------------
__global__ __launch_bounds__(256) void fill_buckets(const int* __restrict__ src,
                                                    const int* __restrict__ dst,
                                                    int* __restrict__ deg,
                                                    int* __restrict__ bucket) {
    int lane = threadIdx.x & 63;
    u32 hiw = ((const u32*)src)[2 * lane + 1];          // int64 => high words all 0
    bool i64 = __popcll(__ballot(hiw == 0u)) >= 48;
    int e = blockIdx.x * 256 + threadIdx.x;
    if (e >= N_EDGES) return;
    int s, d;
    if (i64) { s = src[2 * e]; d = dst[N_EDGES + 2 * e]; }
    else     { s = src[e];     d = dst[e]; }
    int pos = atomicAdd(&deg[d], 1);
    if (pos < CAP) bucket[(size_t)d * CAP + pos] = s;
}

// ---------------- aggregation: out[n] = h[n] + sum_{e: dst=n} h[src[e]] ----------------
__global__ __launch_bounds__(256) void agg_kernel(const u32* __restrict__ h,
                                                  const int* __restrict__ deg,
                                                  const int* __restrict__ bucket,
                                                  u32* __restrict__ out) {
    int w = threadIdx.x >> 6, lane = threadIdx.x & 63;
    bool isbf = probe_bf16(h[lane]);                    // layer1: x fp32; layer2: our bf16
    int node = blockIdx.x * 4 + w;
    if (node >= N_NODES) return;
    int d = deg[node];
    d = d > CAP ? CAP : d;
    const int* bk = bucket + (size_t)node * CAP;
    float ax, ay;
    if (isbf) {
        u32 self = h[(size_t)node * CHW + lane];
        ax = bflo(self); ay = bfhi(self);
        int j = 0;
        for (; j + 4 <= d; j += 4) {
            int s0 = bk[j], s1 = bk[j + 1], s2 = bk[j + 2], s3 = bk[j + 3];
            u32 v0 = h[(size_t)s0 * CHW + lane];
            u32 v1 = h[(size_t)s1 * CHW + lane];
            u32 v2 = h[(size_t)s2 * CHW + lane];
            u32 v3 = h[(size_t)s3 * CHW + lane];
            ax += bflo(v0) + bflo(v1) + bflo(v2) + bflo(v3);
            ay += bfhi(v0) + bfhi(v1) + bfhi(v2) + bfhi(v3);
        }
        for (; j < d; ++j) {
            u32 v = h[(size_t)bk[j] * CHW + lane];
            ax += bflo(v);
            ay += bfhi(v);
        }
    } else {
        const float2* hf = (const float2*)h;
        float2 self = hf[(size_t)node * CHW + lane];
        ax = self.x; ay = self.y;
        int j = 0;
        for (; j + 4 <= d; j += 4) {
            int s0 = bk[j], s1 = bk[j + 1], s2 = bk[j + 2], s3 = bk[j + 3];
            float2 v0 = hf[(size_t)s0 * CHW + lane];
            float2 v1 = hf[(size_t)s1 * CHW + lane];
            float2 v2 = hf[(size_t)s2 * CHW + lane];
            float2 v3 = hf[(size_t)s3 * CHW + lane];
            ax += v0.x + v1.x + v2.x + v3.x;
            ay += v0.y + v1.y + v2.y + v3.y;
        }
        for (; j < d; ++j) {
            float2 v = hf[(size_t)bk[j] * CHW + lane];
            ax += v.x; ay += v.y;
        }
    }
    out[(size_t)node * CHW + lane] = pack2(ax, ay);
}

// ---------------- fused 2-layer MLP: out = relu(relu(in@Wa+ba)@Wb+bb), bf16 MFMA ----------------
__global__ __launch_bounds__(256) void mlp_kernel(const u16* __restrict__ in,
                                                  const u16* __restrict__ Wa,
                                                  const u16* __restrict__ ba,
                                                  const u16* __restrict__ Wb,
                                                  const u16* __restrict__ bb,
                                                  u16* __restrict__ out,
                                                  int nrows) {
    __shared__ __align__(16) u16 Wlds[128 * PAD];  // transposed weight [n][k], bf16
    __shared__ __align__(16) u16 tlds[64 * PAD];   // per-wave 16-row staging [r][k]
    const int tid = threadIdx.x;
    const int w = tid >> 6;
    const int lane = tid & 63;
    const int n16 = lane & 15;
    const int quad = lane >> 4;
    const int row0 = blockIdx.x * 64 + w * 16;
    const bool active = row0 < nrows;   // nrows % 16 == 0 -> whole-wave granularity
    const bool isbf = probe_bf16(((const u32*)Wa)[lane]);   // params share one dtype

    for (int idx = tid; idx < 128 * 128; idx += 256) {
        int k = idx >> 7, n = idx & 127;
        Wlds[n * PAD + k] = isbf ? Wa[idx]
                                 : f2bf(__builtin_bit_cast(float, ((const u32*)Wa)[idx]));
    }
    __syncthreads();

    f32x4 acc[8];
    bf16x8 afrag[4];
    if (active) {
        const u16* rowp = in + (size_t)(row0 + n16) * CH + quad * 8;
#pragma unroll
        for (int ks = 0; ks < 4; ++ks)
            afrag[ks] = *(const bf16x8*)(rowp + ks * 32);
#pragma unroll
        for (int ct = 0; ct < 8; ++ct) {
            f32x4 a = {0.f, 0.f, 0.f, 0.f};
#pragma unroll
            for (int ks = 0; ks < 4; ++ks) {
                bf16x8 b = *(const bf16x8*)&Wlds[(u32)(ct * 16 + n16) * PAD + ks * 32 + quad * 8];
                a = __builtin_amdgcn_mfma_f32_16x16x32_bf16(afrag[ks], b, a, 0, 0, 0);
            }
            acc[ct] = a;
        }
#pragma unroll
        for (int ct = 0; ct < 8; ++ct) {
            float bv = isbf ? bf2f(ba[ct * 16 + n16]) : ((const float*)ba)[ct * 16 + n16];
#pragma unroll
            for (int r = 0; r < 4; ++r) {
                float v = fmaxf(acc[ct][r] + bv, 0.f);
                tlds[(w * 16 + quad * 4 + r) * PAD + ct * 16 + n16] = f2bf(v);
            }
        }
    }
    __syncthreads();
    for (int idx = tid; idx < 128 * 128; idx += 256) {
        int k = idx >> 7, n = idx & 127;
        Wlds[n * PAD + k] = isbf ? Wb[idx]
                                 : f2bf(__builtin_bit_cast(float, ((const u32*)Wb)[idx]));
    }
    __syncthreads();

    if (active) {
#pragma unroll
        for (int ks = 0; ks < 4; ++ks)
            afrag[ks] = *(const bf16x8*)&tlds[(u32)(w * 16 + n16) * PAD + ks * 32 + quad * 8];
#pragma unroll
        for (int ct = 0; ct < 8; ++ct) {
            f32x4 a = {0.f, 0.f, 0.f, 0.f};
#pragma unroll
            for (int ks = 0; ks < 4; ++ks) {
                bf16x8 b = *(const bf16x8*)&Wlds[(u32)(ct * 16 + n16) * PAD + ks * 32 + quad * 8];
                a = __builtin_amdgcn_mfma_f32_16x16x32_bf16(afrag[ks], b, a, 0, 0, 0);
            }
            acc[ct] = a;
        }
#pragma unroll
        for (int ct = 0; ct < 8; ++ct) {
            float bv = isbf ? bf2f(bb[ct * 16 + n16]) : ((const float*)bb)[ct * 16 + n16];
#pragma unroll
            for (int r = 0; r < 4; ++r) {
                float v = fmaxf(acc[ct][r] + bv, 0.f);
                tlds[(w * 16 + quad * 4 + r) * PAD + ct * 16 + n16] = f2bf(v);
            }
        }
        u32* outw = (u32*)out;
        for (int r = 0; r < 16; ++r) {
            u32 v = *(const u32*)&tlds[(w * 16 + r) * PAD + lane * 2];
            outw[(size_t)(row0 + r) * CHW + lane] = v;
        }
    }
}

// ---------------- per-graph node ranges (batch is sorted) ----------------
__global__ __launch_bounds__(256) void graph_bounds(const int* __restrict__ batch,
                                                    int* __restrict__ gstart,
                                                    int* __restrict__ gend) {
    int lane = threadIdx.x & 63;
    // probe mid-array: early batch entries are legitimately 0 (sorted graph ids)
    u32 hiw = ((const u32*)batch)[2 * (12500 + lane) + 1];
    bool i64 = __popcll(__ballot(hiw == 0u)) >= 48;
    int i = blockIdx.x * 256 + threadIdx.x;
    if (i >= N_NODES) return;
    int g = i64 ? batch[2 * i] : batch[i];
    atomicMin(&gstart[g], i);
    atomicMax(&gend[g], i + 1);
}

// ---------------- mean pool: one wave per graph (packed-bf16 input) ----------------
__global__ __launch_bounds__(256) void pool_kernel(const u32* __restrict__ h,
                                                   const int* __restrict__ gstart,
                                                   const int* __restrict__ gend,
                                                   float* __restrict__ pooled) {
    int w = threadIdx.x >> 6, lane = threadIdx.x & 63;
    int g = blockIdx.x * 4 + w;
    if (g >= NG) return;
    int s = gstart[g], e = gend[g];
    float ax = 0.f, ay = 0.f;
    if (s < e) {
        for (int i = s; i < e; ++i) {
            u32 v = h[(size_t)i * CHW + lane];
            ax += bflo(v);
            ay += bfhi(v);
        }
    }
    float inv = 1.f / (float)((s < e) ? (e - s) : 1);
    ((float2*)pooled)[(size_t)g * CHW + lane] = make_float2(ax * inv, ay * inv);
}

// ---------------- head: sigmoid(relu(pooled@Wf1+bf1)@Wf2+bf2), fp32 VALU, fp32 OUT ----------------
__global__ __launch_bounds__(256) void final_kernel(const float* __restrict__ pooled,
                                                    const u16* __restrict__ Wf1,
                                                    const u16* __restrict__ bf1,
                                                    const u16* __restrict__ Wf2,
                                                    const u16* __restrict__ bf2v,
                                                    float* __restrict__ out) {
    __shared__ float rowb[4][128];
    __shared__ float tb[4][128];
    int w = threadIdx.x >> 6, lane = threadIdx.x & 63;
    bool isbf = probe_bf16(((const u32*)Wf1)[lane]);
    int g = blockIdx.x * 4 + w;  // grid exact: 128 blocks * 4 = 512
    float2 rv = ((const float2*)pooled)[(size_t)g * CHW + lane];
    rowb[w][2 * lane] = rv.x;
    rowb[w][2 * lane + 1] = rv.y;
    __syncthreads();
#pragma unroll
    for (int jj = 0; jj < 2; ++jj) {
        int j = lane + jj * 64;
        float a = isbf ? bf2f(bf1[j]) : ((const float*)bf1)[j];
        for (int k = 0; k < 128; ++k) {
            float wv = isbf ? bf2f(Wf1[k * 128 + j]) : ((const float*)Wf1)[k * 128 + j];
            a += rowb[w][k] * wv;
        }
        tb[w][j] = fmaxf(a, 0.f);
    }
    __syncthreads();
    if (lane < 6) {
        float a = isbf ? bf2f(bf2v[lane]) : ((const float*)bf2v)[lane];
        for (int k = 0; k < 128; ++k) {
            float wv = isbf ? bf2f(Wf2[k * 6 + lane]) : ((const float*)Wf2)[k * 6 + lane];
            a += tb[w][k] * wv;
        }
        float s = 1.f / (1.f + __expf(-a));
        out[g * 6 + lane] = s;           // fp32 output — the fix
    }
}

extern "C" void kernel_launch(void* const* d_in, const int* in_sizes, int n_in,
                              void* d_out, int out_size, void* d_ws, size_t ws_size,
                              hipStream_t stream) {
    const u32* x = (const u32*)d_in[0];
    const int* ei = (const int*)d_in[1];
    const int* src = ei;
    const int* dst = ei + N_EDGES;
    const int* batch = (const int*)d_in[2];
    const u16* W1a = (const u16*)d_in[3];
    const u16* b1a = (const u16*)d_in[4];
    const u16* W1b = (const u16*)d_in[5];
    const u16* b1b = (const u16*)d_in[6];
    const u16* W2a = (const u16*)d_in[7];
    const u16* b2a = (const u16*)d_in[8];
    const u16* W2b = (const u16*)d_in[9];
    const u16* b2b = (const u16*)d_in[10];
    const u16* Wf1 = (const u16*)d_in[11];
    const u16* bf1 = (const u16*)d_in[12];
    const u16* Wf2 = (const u16*)d_in[13];
    const u16* bf2v = (const u16*)d_in[14];
    float* out = (float*)d_out;

    char* ws = (char*)d_ws;
    int* deg = (int*)(ws + 0);                 //   200,000 B (pad to 200,192)
    int* bucket = (int*)(ws + 200192);         // 25,600,000 B
    u32* hsum = (u32*)(ws + 25800192);         // 12,800,000 B packed bf16
    u32* h1 = (u32*)(ws + 38600192);           // 12,800,000 B
    u32* h2 = (u32*)(ws + 51400192);           // 12,800,000 B
    float* pooled = (float*)(ws + 64200192);   //    262,144 B
    int* gstart = (int*)(ws + 64462336);       //      2,048 B
    int* gend = (int*)(ws + 64464384);         //      2,048 B

    hipMemsetAsync(deg, 0, (size_t)N_NODES * 4, stream);
    hipMemsetAsync(gstart, 0x7F, NG * 4, stream);
    hipMemsetAsync(gend, 0, NG * 4, stream);

    fill_buckets<<<(N_EDGES + 255) / 256, 256, 0, stream>>>(src, dst, deg, bucket);
    graph_bounds<<<(N_NODES + 255) / 256, 256, 0, stream>>>(batch, gstart, gend);

    // layer 1: x -> hsum -> h1
    agg_kernel<<<(N_NODES + 3) / 4, 256, 0, stream>>>(x, deg, bucket, hsum);
    mlp_kernel<<<(N_NODES + 63) / 64, 256, 0, stream>>>((const u16*)hsum, W1a, b1a, W1b, b1b,
                                                        (u16*)h1, N_NODES);
    // layer 2: h1 -> hsum -> h2
    agg_kernel<<<(N_NODES + 3) / 4, 256, 0, stream>>>(h1, deg, bucket, hsum);
    mlp_kernel<<<(N_NODES + 63) / 64, 256, 0, stream>>>((const u16*)hsum, W2a, b2a, W2b, b2b,
                                                        (u16*)h2, N_NODES);
    // pool + head
    pool_kernel<<<(NG + 3) / 4, 256, 0, stream>>>(h2, gstart, gend, pooled);
    final_kernel<<<NG / 4, 256, 0, stream>>>(pooled, Wf1, bf1, Wf2, bf2v, out);
}

// Round 9
// 444.940 us; speedup vs baseline: 1.4028x; 1.4028x over previous
//
#include <hip/hip_runtime.h>

typedef unsigned short u16;
typedef unsigned int u32;

#define N_NODES 50000
#define N_EDGES 1600000
#define CH 128
#define CHW 64          // u32 words per packed-bf16 row
#define NG 512
#define CAP 128         // bucket capacity per node (Poisson(32): P(>=128) ~ 1e-43)
#define PAD 136         // LDS row stride in bf16 elems (272B: 16B-aligned, bank-spread)

typedef __bf16 bf16x8 __attribute__((ext_vector_type(8)));
typedef float f32x4 __attribute__((ext_vector_type(4)));

// ---- workspace byte offsets (total ~51.9 MB; <= proven-writable 64.5 MB) ----
#define OFF_DEG 0ull
#define OFF_BUCKET 200192ull      // u16 bucket, 12,800,000 B
#define OFF_XB 13000192ull        // 12.8 MB packed-bf16 x; reused as h2
#define OFF_HSUM 25800192ull      // 12.8 MB
#define OFF_H1 38600192ull        // 12.8 MB
#define OFF_POOL 51400192ull      // 262,144 B
#define OFF_GS 51662336ull        // 2,048 B
#define OFF_GE 51664384ull        // 2,048 B
#define OFF_WT 51666432ull        // 4 x 32,768 B bf16 transposed weights [n][k]
#define OFF_BC 51797504ull        // 4 x 512 B fp32 biases
#define OFF_WF1 51799552ull       // 65,536 B fp32
#define OFF_BF1 51865088ull       // 512 B
#define OFF_WF2 51865600ull       // 3,072 B
#define OFF_BF2 51868672ull       // 32 B

__device__ __forceinline__ float bflo(u32 v) { return __builtin_bit_cast(float, v << 16); }
__device__ __forceinline__ float bfhi(u32 v) { return __builtin_bit_cast(float, v & 0xffff0000u); }
__device__ __forceinline__ float bf2f(u16 v) { return __builtin_bit_cast(float, ((u32)v) << 16); }
__device__ __forceinline__ u16 f2bf(float f) {
    u32 x = __builtin_bit_cast(u32, f);
    x += 0x7fffu + ((x >> 16) & 1u);   // RNE
    return (u16)(x >> 16);
}
__device__ __forceinline__ u32 pack2(float a, float b) {
    return (u32)f2bf(a) | ((u32)f2bf(b) << 16);
}
// wave-ballot probe: true if the 64 sampled u32 words look like packed bf16 pairs
__device__ __forceinline__ bool probe_bf16(u32 w0) {
    u32 ex = (w0 >> 7) & 0xFFu;
    bool ok = ((w0 & 0x7FFFu) == 0u) || (ex >= 0x70u && ex <= 0x8Fu);
    return __popcll(__ballot(ok)) >= 48;
}
__device__ __forceinline__ float loadf(const void* p, int i, bool isbf) {
    return isbf ? bf2f(((const u16*)p)[i]) : ((const float*)p)[i];
}

// ---------------- one-time param canonicalization ----------------
// weights -> bf16 TRANSPOSED [n][k]; biases + head -> fp32
__global__ __launch_bounds__(256) void prep_params(char* ws,
                                                   const void* W0, const void* W1,
                                                   const void* W2, const void* W3,
                                                   const void* b0, const void* b1,
                                                   const void* b2, const void* b3,
                                                   const void* Wf1, const void* bf1,
                                                   const void* Wf2, const void* bf2) {
    int lane = threadIdx.x & 63;
    bool isbf = probe_bf16(((const u32*)W0)[lane]);
    int idx = blockIdx.x * 256 + threadIdx.x;
    u16* Wt = (u16*)(ws + OFF_WT);
    float* bc = (float*)(ws + OFF_BC);
    float* Wf1c = (float*)(ws + OFF_WF1);
    float* bf1c = (float*)(ws + OFF_BF1);
    float* Wf2c = (float*)(ws + OFF_WF2);
    float* bf2c = (float*)(ws + OFF_BF2);
    if (idx < 65536) {                       // 4 weights, 16384 each: Wt[j][n*128+k] = W[j][k*128+n]
        int j = idx >> 14, r = idx & 16383;
        int n = r >> 7, k = r & 127;
        const void* src = (j == 0) ? W0 : (j == 1) ? W1 : (j == 2) ? W2 : W3;
        float v = loadf(src, k * 128 + n, isbf);
        Wt[idx] = f2bf(v);
    } else if (idx < 66048) {                // 4 biases, 128 each
        int r = idx - 65536, j = r >> 7, c = r & 127;
        const void* src = (j == 0) ? b0 : (j == 1) ? b1 : (j == 2) ? b2 : b3;
        bc[r] = loadf(src, c, isbf);
    } else if (idx < 82432) {
        Wf1c[idx - 66048] = loadf(Wf1, idx - 66048, isbf);
    } else if (idx < 82560) {
        bf1c[idx - 82432] = loadf(bf1, idx - 82432, isbf);
    } else if (idx < 83328) {
        Wf2c[idx - 82560] = loadf(Wf2, idx - 82560, isbf);
    } else if (idx < 83334) {
        bf2c[idx - 83328] = loadf(bf2, idx - 83328, isbf);
    }
}

// ---------------- x -> packed bf16 (once) ----------------
__global__ __launch_bounds__(256) void cvt_x(const u32* __restrict__ x, u32* __restrict__ xb) {
    int lane = threadIdx.x & 63;
    bool isbf = probe_bf16(x[lane]);
    int i = blockIdx.x * 256 + threadIdx.x;
    if (i >= N_NODES * CHW) return;
    if (isbf) {
        xb[i] = x[i];
    } else {
        float2 v = ((const float2*)x)[i];
        xb[i] = pack2(v.x, v.y);
    }
}

// ---------------- bucket build (u16 entries: 1 cache line per node avg) ----------------
__global__ __launch_bounds__(256) void fill_buckets(const int* __restrict__ src,
                                                    const int* __restrict__ dst,
                                                    int* __restrict__ deg,
                                                    u16* __restrict__ bucket) {
    int lane = threadIdx.x & 63;
    u32 hiw = ((const u32*)src)[2 * lane + 1];          // int64 => high words all 0
    bool i64 = __popcll(__ballot(hiw == 0u)) >= 48;
    int e = blockIdx.x * 256 + threadIdx.x;
    if (e >= N_EDGES) return;
    int s, d;
    if (i64) { s = src[2 * e]; d = dst[N_EDGES + 2 * e]; }
    else     { s = src[e];     d = dst[e]; }
    int pos = atomicAdd(&deg[d], 1);
    if (pos < CAP) bucket[(size_t)d * CAP + pos] = (u16)s;
}

// ---------------- aggregation: out[n] = h[n] + sum h[src], packed-bf16 in/out ----------------
__global__ __launch_bounds__(256) void agg_kernel(const u32* __restrict__ h,
                                                  const int* __restrict__ deg,
                                                  const u16* __restrict__ bucket,
                                                  u32* __restrict__ out) {
    int w = threadIdx.x >> 6, lane = threadIdx.x & 63;
    int node = blockIdx.x * 4 + w;
    if (node >= N_NODES) return;
    u32 self = h[(size_t)node * CHW + lane];
    float ax = bflo(self), ay = bfhi(self);
    int d = deg[node];
    d = d > CAP ? CAP : d;
    const u16* bk = bucket + (size_t)node * CAP;
    const u32* bkw = (const u32*)bk;            // 2 ids per word, 256B-aligned
    int j = 0;
    for (; j + 8 <= d; j += 8) {                // 8 gathers in flight
        u32 w0 = bkw[(j >> 1) + 0], w1 = bkw[(j >> 1) + 1];
        u32 w2 = bkw[(j >> 1) + 2], w3 = bkw[(j >> 1) + 3];
        u32 v0 = h[(size_t)(w0 & 0xFFFFu) * CHW + lane];
        u32 v1 = h[(size_t)(w0 >> 16) * CHW + lane];
        u32 v2 = h[(size_t)(w1 & 0xFFFFu) * CHW + lane];
        u32 v3 = h[(size_t)(w1 >> 16) * CHW + lane];
        u32 v4 = h[(size_t)(w2 & 0xFFFFu) * CHW + lane];
        u32 v5 = h[(size_t)(w2 >> 16) * CHW + lane];
        u32 v6 = h[(size_t)(w3 & 0xFFFFu) * CHW + lane];
        u32 v7 = h[(size_t)(w3 >> 16) * CHW + lane];
        ax += bflo(v0) + bflo(v1) + bflo(v2) + bflo(v3)
            + bflo(v4) + bflo(v5) + bflo(v6) + bflo(v7);
        ay += bfhi(v0) + bfhi(v1) + bfhi(v2) + bfhi(v3)
            + bfhi(v4) + bfhi(v5) + bfhi(v6) + bfhi(v7);
    }
    for (; j < d; ++j) {
        u32 v = h[(size_t)bk[j] * CHW + lane];
        ax += bflo(v);
        ay += bfhi(v);
    }
    out[(size_t)node * CHW + lane] = pack2(ax, ay);
}

// ---------------- fused 2-layer MLP: out = relu(relu(in@Wa+ba)@Wb+bb), bf16 MFMA ----------------
// Wta/Wtb are canonical bf16 TRANSPOSED [n][k] -> pure vector staging, no convert
__global__ __launch_bounds__(256) void mlp_kernel(const u16* __restrict__ in,
                                                  const u16* __restrict__ Wta,
                                                  const float* __restrict__ ba,
                                                  const u16* __restrict__ Wtb,
                                                  const float* __restrict__ bb,
                                                  u16* __restrict__ out,
                                                  int nrows) {
    __shared__ __align__(16) u16 Wlds[128 * PAD];  // [n][k]
    __shared__ __align__(16) u16 tlds[64 * PAD];   // per-wave 16-row staging [r][k]
    const int tid = threadIdx.x;
    const int w = tid >> 6;
    const int lane = tid & 63;
    const int n16 = lane & 15;
    const int quad = lane >> 4;
    const int row0 = blockIdx.x * 64 + w * 16;
    const bool active = row0 < nrows;

    {   // stage Wa: 2048 x 16B copies, 8 per thread
        const uint4* wsrc = (const uint4*)Wta;
#pragma unroll
        for (int it = 0; it < 8; ++it) {
            int idx = tid + it * 256;
            int n = idx >> 4, c = idx & 15;
            *(uint4*)&Wlds[n * PAD + c * 8] = wsrc[idx];
        }
    }
    __syncthreads();

    f32x4 acc[8];
    bf16x8 afrag[4];
    if (active) {
        const u16* rowp = in + (size_t)(row0 + n16) * CH + quad * 8;
#pragma unroll
        for (int ks = 0; ks < 4; ++ks)
            afrag[ks] = *(const bf16x8*)(rowp + ks * 32);
#pragma unroll
        for (int ct = 0; ct < 8; ++ct) {
            f32x4 a = {0.f, 0.f, 0.f, 0.f};
#pragma unroll
            for (int ks = 0; ks < 4; ++ks) {
                bf16x8 b = *(const bf16x8*)&Wlds[(u32)(ct * 16 + n16) * PAD + ks * 32 + quad * 8];
                a = __builtin_amdgcn_mfma_f32_16x16x32_bf16(afrag[ks], b, a, 0, 0, 0);
            }
            acc[ct] = a;
        }
#pragma unroll
        for (int ct = 0; ct < 8; ++ct) {
            float bv = ba[ct * 16 + n16];
#pragma unroll
            for (int r = 0; r < 4; ++r) {
                float v = fmaxf(acc[ct][r] + bv, 0.f);
                tlds[(w * 16 + quad * 4 + r) * PAD + ct * 16 + n16] = f2bf(v);
            }
        }
    }
    __syncthreads();
    {   // stage Wb
        const uint4* wsrc = (const uint4*)Wtb;
#pragma unroll
        for (int it = 0; it < 8; ++it) {
            int idx = tid + it * 256;
            int n = idx >> 4, c = idx & 15;
            *(uint4*)&Wlds[n * PAD + c * 8] = wsrc[idx];
        }
    }
    __syncthreads();

    if (active) {
#pragma unroll
        for (int ks = 0; ks < 4; ++ks)
            afrag[ks] = *(const bf16x8*)&tlds[(u32)(w * 16 + n16) * PAD + ks * 32 + quad * 8];
#pragma unroll
        for (int ct = 0; ct < 8; ++ct) {
            f32x4 a = {0.f, 0.f, 0.f, 0.f};
#pragma unroll
            for (int ks = 0; ks < 4; ++ks) {
                bf16x8 b = *(const bf16x8*)&Wlds[(u32)(ct * 16 + n16) * PAD + ks * 32 + quad * 8];
                a = __builtin_amdgcn_mfma_f32_16x16x32_bf16(afrag[ks], b, a, 0, 0, 0);
            }
            acc[ct] = a;
        }
#pragma unroll
        for (int ct = 0; ct < 8; ++ct) {
            float bv = bb[ct * 16 + n16];
#pragma unroll
            for (int r = 0; r < 4; ++r) {
                float v = fmaxf(acc[ct][r] + bv, 0.f);
                tlds[(w * 16 + quad * 4 + r) * PAD + ct * 16 + n16] = f2bf(v);
            }
        }
        u32* outw = (u32*)out;
        for (int r = 0; r < 16; ++r) {
            u32 v = *(const u32*)&tlds[(w * 16 + r) * PAD + lane * 2];
            outw[(size_t)(row0 + r) * CHW + lane] = v;
        }
    }
}

// ---------------- per-graph node ranges (batch is sorted) ----------------
__global__ __launch_bounds__(256) void graph_bounds(const int* __restrict__ batch,
                                                    int* __restrict__ gstart,
                                                    int* __restrict__ gend) {
    int lane = threadIdx.x & 63;
    u32 hiw = ((const u32*)batch)[2 * (12500 + lane) + 1];   // mid-array: ids nonzero if int32
    bool i64 = __popcll(__ballot(hiw == 0u)) >= 48;
    int i = blockIdx.x * 256 + threadIdx.x;
    if (i >= N_NODES) return;
    int g = i64 ? batch[2 * i] : batch[i];
    atomicMin(&gstart[g], i);
    atomicMax(&gend[g], i + 1);
}

// ---------------- mean pool: one wave per graph ----------------
__global__ __launch_bounds__(256) void pool_kernel(const u32* __restrict__ h,
                                                   const int* __restrict__ gstart,
                                                   const int* __restrict__ gend,
                                                   float* __restrict__ pooled) {
    int w = threadIdx.x >> 6, lane = threadIdx.x & 63;
    int g = blockIdx.x * 4 + w;
    if (g >= NG) return;
    int s = gstart[g], e = gend[g];
    float ax = 0.f, ay = 0.f;
    if (s < e) {
        for (int i = s; i < e; ++i) {
            u32 v = h[(size_t)i * CHW + lane];
            ax += bflo(v);
            ay += bfhi(v);
        }
    }
    float inv = 1.f / (float)((s < e) ? (e - s) : 1);
    ((float2*)pooled)[(size_t)g * CHW + lane] = make_float2(ax * inv, ay * inv);
}

// ---------------- head: sigmoid(relu(pooled@Wf1+bf1)@Wf2+bf2), fp32, fp32 out ----------------
__global__ __launch_bounds__(256) void final_kernel(const float* __restrict__ pooled,
                                                    const float* __restrict__ Wf1,
                                                    const float* __restrict__ bf1,
                                                    const float* __restrict__ Wf2,
                                                    const float* __restrict__ bf2v,
                                                    float* __restrict__ out) {
    __shared__ float rowb[4][128];
    __shared__ float tb[4][128];
    int w = threadIdx.x >> 6, lane = threadIdx.x & 63;
    int g = blockIdx.x * 4 + w;  // grid exact: 128 * 4 = 512
    float2 rv = ((const float2*)pooled)[(size_t)g * CHW + lane];
    rowb[w][2 * lane] = rv.x;
    rowb[w][2 * lane + 1] = rv.y;
    __syncthreads();
#pragma unroll
    for (int jj = 0; jj < 2; ++jj) {
        int j = lane + jj * 64;
        float a = bf1[j];
        for (int k = 0; k < 128; ++k) a += rowb[w][k] * Wf1[k * 128 + j];
        tb[w][j] = fmaxf(a, 0.f);
    }
    __syncthreads();
    if (lane < 6) {
        float a = bf2v[lane];
        for (int k = 0; k < 128; ++k) a += tb[w][k] * Wf2[k * 6 + lane];
        out[g * 6 + lane] = 1.f / (1.f + __expf(-a));
    }
}

extern "C" void kernel_launch(void* const* d_in, const int* in_sizes, int n_in,
                              void* d_out, int out_size, void* d_ws, size_t ws_size,
                              hipStream_t stream) {
    const u32* x = (const u32*)d_in[0];
    const int* ei = (const int*)d_in[1];
    const int* src = ei;
    const int* dst = ei + N_EDGES;
    const int* batch = (const int*)d_in[2];
    float* out = (float*)d_out;

    char* ws = (char*)d_ws;
    int* deg = (int*)(ws + OFF_DEG);
    u16* bucket = (u16*)(ws + OFF_BUCKET);
    u32* XB = (u32*)(ws + OFF_XB);          // bf16 x; reused as h2
    u32* HSUM = (u32*)(ws + OFF_HSUM);
    u32* H1 = (u32*)(ws + OFF_H1);
    float* pooled = (float*)(ws + OFF_POOL);
    int* gstart = (int*)(ws + OFF_GS);
    int* gend = (int*)(ws + OFF_GE);
    u16* Wt = (u16*)(ws + OFF_WT);
    float* bc = (float*)(ws + OFF_BC);
    float* Wf1c = (float*)(ws + OFF_WF1);
    float* bf1c = (float*)(ws + OFF_BF1);
    float* Wf2c = (float*)(ws + OFF_WF2);
    float* bf2c = (float*)(ws + OFF_BF2);

    hipMemsetAsync(deg, 0, (size_t)N_NODES * 4, stream);
    hipMemsetAsync(gstart, 0x7F, NG * 4, stream);
    hipMemsetAsync(gend, 0, NG * 4, stream);

    prep_params<<<326, 256, 0, stream>>>(ws,
        d_in[3], d_in[5], d_in[7], d_in[9],      // W1a, W1b, W2a, W2b
        d_in[4], d_in[6], d_in[8], d_in[10],     // b1a, b1b, b2a, b2b
        d_in[11], d_in[12], d_in[13], d_in[14]); // Wf1, bf1, Wf2, bf2
    cvt_x<<<(N_NODES * CHW) / 256, 256, 0, stream>>>(x, XB);
    fill_buckets<<<(N_EDGES + 255) / 256, 256, 0, stream>>>(src, dst, deg, bucket);
    graph_bounds<<<(N_NODES + 255) / 256, 256, 0, stream>>>(batch, gstart, gend);

    // layer 1: XB -> HSUM -> H1
    agg_kernel<<<(N_NODES + 3) / 4, 256, 0, stream>>>(XB, deg, bucket, HSUM);
    mlp_kernel<<<(N_NODES + 63) / 64, 256, 0, stream>>>((const u16*)HSUM, Wt, bc,
                                                        Wt + 16384, bc + 128, (u16*)H1, N_NODES);
    // layer 2: H1 -> HSUM -> XB (reused as h2)
    agg_kernel<<<(N_NODES + 3) / 4, 256, 0, stream>>>(H1, deg, bucket, HSUM);
    mlp_kernel<<<(N_NODES + 63) / 64, 256, 0, stream>>>((const u16*)HSUM, Wt + 32768, bc + 256,
                                                        Wt + 49152, bc + 384, (u16*)XB, N_NODES);
    // pool + head
    pool_kernel<<<(NG + 3) / 4, 256, 0, stream>>>(XB, gstart, gend, pooled);
    final_kernel<<<NG / 4, 256, 0, stream>>>(pooled, Wf1c, bf1c, Wf2c, bf2c, out);
}

// Round 10
// 421.157 us; speedup vs baseline: 1.4820x; 1.0565x over previous
//
#include <hip/hip_runtime.h>

typedef unsigned short u16;
typedef unsigned int u32;

#define N_NODES 50000
#define N_EDGES 1600000
#define CH 128
#define CHW 64          // u32 words per packed-bf16 row
#define NG 512
#define CAP 128         // bucket capacity per node (Poisson(32): P(>=128) ~ 1e-43)
#define PAD 136         // LDS row stride in bf16 elems (272B: 16B-aligned, bank-spread)
#define DEGS 16         // deg stride in ints: one counter per 64B line (atomic line-bounce fix)

typedef __bf16 bf16x8 __attribute__((ext_vector_type(8)));
typedef float f32x4 __attribute__((ext_vector_type(4)));

// ---- workspace byte offsets (total ~54.9 MB; <= proven-writable 64.5 MB) ----
#define OFF_DEG 0ull              // 50000*64 B = 3,200,000 (padded atomics)
#define OFF_BUCKET 3200256ull     // u16 bucket, 12,800,000 B
#define OFF_XB 16000256ull        // 12.8 MB packed-bf16 x; reused as h2
#define OFF_HSUM 28800256ull      // 12.8 MB
#define OFF_H1 41600256ull        // 12.8 MB
#define OFF_POOL 54400256ull      // 262,144 B
#define OFF_GS 54662400ull        // 2,048 B
#define OFF_GE 54664448ull        // 2,048 B
#define OFF_WT 54666496ull        // 4 x 32,768 B bf16 transposed weights [n][k]
#define OFF_BC 54797568ull        // 4 x 512 B fp32 biases
#define OFF_WF1 54799616ull       // 65,536 B fp32
#define OFF_BF1 54865152ull       // 512 B
#define OFF_WF2 54865664ull       // 3,072 B
#define OFF_BF2 54868736ull       // 32 B

__device__ __forceinline__ float bflo(u32 v) { return __builtin_bit_cast(float, v << 16); }
__device__ __forceinline__ float bfhi(u32 v) { return __builtin_bit_cast(float, v & 0xffff0000u); }
__device__ __forceinline__ float bf2f(u16 v) { return __builtin_bit_cast(float, ((u32)v) << 16); }
__device__ __forceinline__ u16 f2bf(float f) {
    u32 x = __builtin_bit_cast(u32, f);
    x += 0x7fffu + ((x >> 16) & 1u);   // RNE
    return (u16)(x >> 16);
}
__device__ __forceinline__ u32 pack2(float a, float b) {
    return (u32)f2bf(a) | ((u32)f2bf(b) << 16);
}
// wave-ballot probe: true if the 64 sampled u32 words look like packed bf16 pairs
__device__ __forceinline__ bool probe_bf16(u32 w0) {
    u32 ex = (w0 >> 7) & 0xFFu;
    bool ok = ((w0 & 0x7FFFu) == 0u) || (ex >= 0x70u && ex <= 0x8Fu);
    return __popcll(__ballot(ok)) >= 48;
}
__device__ __forceinline__ float loadf(const void* p, int i, bool isbf) {
    return isbf ? bf2f(((const u16*)p)[i]) : ((const float*)p)[i];
}

// ---------------- one-time param canonicalization ----------------
// weights -> bf16 TRANSPOSED [n][k]; biases + head -> fp32
__global__ __launch_bounds__(256) void prep_params(char* ws,
                                                   const void* W0, const void* W1,
                                                   const void* W2, const void* W3,
                                                   const void* b0, const void* b1,
                                                   const void* b2, const void* b3,
                                                   const void* Wf1, const void* bf1,
                                                   const void* Wf2, const void* bf2) {
    int lane = threadIdx.x & 63;
    bool isbf = probe_bf16(((const u32*)W0)[lane]);
    int idx = blockIdx.x * 256 + threadIdx.x;
    u16* Wt = (u16*)(ws + OFF_WT);
    float* bc = (float*)(ws + OFF_BC);
    float* Wf1c = (float*)(ws + OFF_WF1);
    float* bf1c = (float*)(ws + OFF_BF1);
    float* Wf2c = (float*)(ws + OFF_WF2);
    float* bf2c = (float*)(ws + OFF_BF2);
    if (idx < 65536) {                       // 4 weights, 16384 each: Wt[j][n*128+k] = W[j][k*128+n]
        int j = idx >> 14, r = idx & 16383;
        int n = r >> 7, k = r & 127;
        const void* src = (j == 0) ? W0 : (j == 1) ? W1 : (j == 2) ? W2 : W3;
        float v = loadf(src, k * 128 + n, isbf);
        Wt[idx] = f2bf(v);
    } else if (idx < 66048) {                // 4 biases, 128 each
        int r = idx - 65536, j = r >> 7, c = r & 127;
        const void* src = (j == 0) ? b0 : (j == 1) ? b1 : (j == 2) ? b2 : b3;
        bc[r] = loadf(src, c, isbf);
    } else if (idx < 82432) {
        Wf1c[idx - 66048] = loadf(Wf1, idx - 66048, isbf);
    } else if (idx < 82560) {
        bf1c[idx - 82432] = loadf(bf1, idx - 82432, isbf);
    } else if (idx < 83328) {
        Wf2c[idx - 82560] = loadf(Wf2, idx - 82560, isbf);
    } else if (idx < 83334) {
        bf2c[idx - 83328] = loadf(bf2, idx - 83328, isbf);
    }
}

// ---------------- x -> packed bf16 (once) ----------------
__global__ __launch_bounds__(256) void cvt_x(const u32* __restrict__ x, u32* __restrict__ xb) {
    int lane = threadIdx.x & 63;
    bool isbf = probe_bf16(x[lane]);
    int i = blockIdx.x * 256 + threadIdx.x;
    if (i >= N_NODES * CHW) return;
    if (isbf) {
        xb[i] = x[i];
    } else {
        float2 v = ((const float2*)x)[i];
        xb[i] = pack2(v.x, v.y);
    }
}

// ---------------- bucket build (deg: one counter per cache line) ----------------
__global__ __launch_bounds__(256) void fill_buckets(const int* __restrict__ src,
                                                    const int* __restrict__ dst,
                                                    int* __restrict__ deg,
                                                    u16* __restrict__ bucket) {
    int lane = threadIdx.x & 63;
    u32 hiw = ((const u32*)src)[2 * lane + 1];          // int64 => high words all 0
    bool i64 = __popcll(__ballot(hiw == 0u)) >= 48;
    int e = blockIdx.x * 256 + threadIdx.x;
    if (e >= N_EDGES) return;
    int s, d;
    if (i64) { s = src[2 * e]; d = dst[N_EDGES + 2 * e]; }
    else     { s = src[e];     d = dst[e]; }
    int pos = atomicAdd(&deg[d * DEGS], 1);
    if (pos < CAP) bucket[(size_t)d * CAP + pos] = (u16)s;
}

// ---------------- aggregation: out[n] = h[n] + sum h[src], packed-bf16 in/out ----------------
__global__ __launch_bounds__(256) void agg_kernel(const u32* __restrict__ h,
                                                  const int* __restrict__ deg,
                                                  const u16* __restrict__ bucket,
                                                  u32* __restrict__ out) {
    int w = threadIdx.x >> 6, lane = threadIdx.x & 63;
    int node = blockIdx.x * 4 + w;
    if (node >= N_NODES) return;
    u32 self = h[(size_t)node * CHW + lane];
    float ax = bflo(self), ay = bfhi(self);
    int d = deg[node * DEGS];
    d = d > CAP ? CAP : d;
    const u16* bk = bucket + (size_t)node * CAP;
    const u32* bkw = (const u32*)bk;            // 2 ids per word, 256B-aligned
    int j = 0;
    for (; j + 8 <= d; j += 8) {                // 8 gathers in flight
        u32 w0 = bkw[(j >> 1) + 0], w1 = bkw[(j >> 1) + 1];
        u32 w2 = bkw[(j >> 1) + 2], w3 = bkw[(j >> 1) + 3];
        u32 v0 = h[(size_t)(w0 & 0xFFFFu) * CHW + lane];
        u32 v1 = h[(size_t)(w0 >> 16) * CHW + lane];
        u32 v2 = h[(size_t)(w1 & 0xFFFFu) * CHW + lane];
        u32 v3 = h[(size_t)(w1 >> 16) * CHW + lane];
        u32 v4 = h[(size_t)(w2 & 0xFFFFu) * CHW + lane];
        u32 v5 = h[(size_t)(w2 >> 16) * CHW + lane];
        u32 v6 = h[(size_t)(w3 & 0xFFFFu) * CHW + lane];
        u32 v7 = h[(size_t)(w3 >> 16) * CHW + lane];
        ax += bflo(v0) + bflo(v1) + bflo(v2) + bflo(v3)
            + bflo(v4) + bflo(v5) + bflo(v6) + bflo(v7);
        ay += bfhi(v0) + bfhi(v1) + bfhi(v2) + bfhi(v3)
            + bfhi(v4) + bfhi(v5) + bfhi(v6) + bfhi(v7);
    }
    for (; j < d; ++j) {
        u32 v = h[(size_t)bk[j] * CHW + lane];
        ax += bflo(v);
        ay += bfhi(v);
    }
    out[(size_t)node * CHW + lane] = pack2(ax, ay);
}

// ---------------- fused 2-layer MLP: out = relu(relu(in@Wa+ba)@Wb+bb), bf16 MFMA ----------------
__global__ __launch_bounds__(256) void mlp_kernel(const u16* __restrict__ in,
                                                  const u16* __restrict__ Wta,
                                                  const float* __restrict__ ba,
                                                  const u16* __restrict__ Wtb,
                                                  const float* __restrict__ bb,
                                                  u16* __restrict__ out,
                                                  int nrows) {
    __shared__ __align__(16) u16 Wlds[128 * PAD];  // [n][k]
    __shared__ __align__(16) u16 tlds[64 * PAD];   // per-wave 16-row staging [r][k]
    const int tid = threadIdx.x;
    const int w = tid >> 6;
    const int lane = tid & 63;
    const int n16 = lane & 15;
    const int quad = lane >> 4;
    const int row0 = blockIdx.x * 64 + w * 16;
    const bool active = row0 < nrows;

    {   // stage Wa: 2048 x 16B copies, 8 per thread
        const uint4* wsrc = (const uint4*)Wta;
#pragma unroll
        for (int it = 0; it < 8; ++it) {
            int idx = tid + it * 256;
            int n = idx >> 4, c = idx & 15;
            *(uint4*)&Wlds[n * PAD + c * 8] = wsrc[idx];
        }
    }
    __syncthreads();

    f32x4 acc[8];
    bf16x8 afrag[4];
    if (active) {
        const u16* rowp = in + (size_t)(row0 + n16) * CH + quad * 8;
#pragma unroll
        for (int ks = 0; ks < 4; ++ks)
            afrag[ks] = *(const bf16x8*)(rowp + ks * 32);
#pragma unroll
        for (int ct = 0; ct < 8; ++ct) {
            f32x4 a = {0.f, 0.f, 0.f, 0.f};
#pragma unroll
            for (int ks = 0; ks < 4; ++ks) {
                bf16x8 b = *(const bf16x8*)&Wlds[(u32)(ct * 16 + n16) * PAD + ks * 32 + quad * 8];
                a = __builtin_amdgcn_mfma_f32_16x16x32_bf16(afrag[ks], b, a, 0, 0, 0);
            }
            acc[ct] = a;
        }
#pragma unroll
        for (int ct = 0; ct < 8; ++ct) {
            float bv = ba[ct * 16 + n16];
#pragma unroll
            for (int r = 0; r < 4; ++r) {
                float v = fmaxf(acc[ct][r] + bv, 0.f);
                tlds[(w * 16 + quad * 4 + r) * PAD + ct * 16 + n16] = f2bf(v);
            }
        }
    }
    __syncthreads();
    {   // stage Wb
        const uint4* wsrc = (const uint4*)Wtb;
#pragma unroll
        for (int it = 0; it < 8; ++it) {
            int idx = tid + it * 256;
            int n = idx >> 4, c = idx & 15;
            *(uint4*)&Wlds[n * PAD + c * 8] = wsrc[idx];
        }
    }
    __syncthreads();

    if (active) {
#pragma unroll
        for (int ks = 0; ks < 4; ++ks)
            afrag[ks] = *(const bf16x8*)&tlds[(u32)(w * 16 + n16) * PAD + ks * 32 + quad * 8];
#pragma unroll
        for (int ct = 0; ct < 8; ++ct) {
            f32x4 a = {0.f, 0.f, 0.f, 0.f};
#pragma unroll
            for (int ks = 0; ks < 4; ++ks) {
                bf16x8 b = *(const bf16x8*)&Wlds[(u32)(ct * 16 + n16) * PAD + ks * 32 + quad * 8];
                a = __builtin_amdgcn_mfma_f32_16x16x32_bf16(afrag[ks], b, a, 0, 0, 0);
            }
            acc[ct] = a;
        }
#pragma unroll
        for (int ct = 0; ct < 8; ++ct) {
            float bv = bb[ct * 16 + n16];
#pragma unroll
            for (int r = 0; r < 4; ++r) {
                float v = fmaxf(acc[ct][r] + bv, 0.f);
                tlds[(w * 16 + quad * 4 + r) * PAD + ct * 16 + n16] = f2bf(v);
            }
        }
        u32* outw = (u32*)out;
        for (int r = 0; r < 16; ++r) {
            u32 v = *(const u32*)&tlds[(w * 16 + r) * PAD + lane * 2];
            outw[(size_t)(row0 + r) * CHW + lane] = v;
        }
    }
}

// ---------------- per-graph node ranges (batch is sorted) ----------------
__global__ __launch_bounds__(256) void graph_bounds(const int* __restrict__ batch,
                                                    int* __restrict__ gstart,
                                                    int* __restrict__ gend) {
    int lane = threadIdx.x & 63;
    u32 hiw = ((const u32*)batch)[2 * (12500 + lane) + 1];   // mid-array: ids nonzero if int32
    bool i64 = __popcll(__ballot(hiw == 0u)) >= 48;
    int i = blockIdx.x * 256 + threadIdx.x;
    if (i >= N_NODES) return;
    int g = i64 ? batch[2 * i] : batch[i];
    atomicMin(&gstart[g], i);
    atomicMax(&gend[g], i + 1);
}

// ---------------- mean pool: one wave per graph, 4-deep ILP ----------------
__global__ __launch_bounds__(256) void pool_kernel(const u32* __restrict__ h,
                                                   const int* __restrict__ gstart,
                                                   const int* __restrict__ gend,
                                                   float* __restrict__ pooled) {
    int w = threadIdx.x >> 6, lane = threadIdx.x & 63;
    int g = blockIdx.x * 4 + w;
    if (g >= NG) return;
    int s = gstart[g], e = gend[g];
    float ax = 0.f, ay = 0.f;
    if (s < e) {
        int i = s;
        for (; i + 4 <= e; i += 4) {
            u32 v0 = h[(size_t)(i + 0) * CHW + lane];
            u32 v1 = h[(size_t)(i + 1) * CHW + lane];
            u32 v2 = h[(size_t)(i + 2) * CHW + lane];
            u32 v3 = h[(size_t)(i + 3) * CHW + lane];
            ax += bflo(v0) + bflo(v1) + bflo(v2) + bflo(v3);
            ay += bfhi(v0) + bfhi(v1) + bfhi(v2) + bfhi(v3);
        }
        for (; i < e; ++i) {
            u32 v = h[(size_t)i * CHW + lane];
            ax += bflo(v);
            ay += bfhi(v);
        }
    }
    float inv = 1.f / (float)((s < e) ? (e - s) : 1);
    ((float2*)pooled)[(size_t)g * CHW + lane] = make_float2(ax * inv, ay * inv);
}

// ---------------- head: sigmoid(relu(pooled@Wf1+bf1)@Wf2+bf2), fp32, fp32 out ----------------
__global__ __launch_bounds__(256) void final_kernel(const float* __restrict__ pooled,
                                                    const float* __restrict__ Wf1,
                                                    const float* __restrict__ bf1,
                                                    const float* __restrict__ Wf2,
                                                    const float* __restrict__ bf2v,
                                                    float* __restrict__ out) {
    __shared__ float rowb[4][128];
    __shared__ float tb[4][128];
    int w = threadIdx.x >> 6, lane = threadIdx.x & 63;
    int g = blockIdx.x * 4 + w;  // grid exact: 128 * 4 = 512
    float2 rv = ((const float2*)pooled)[(size_t)g * CHW + lane];
    rowb[w][2 * lane] = rv.x;
    rowb[w][2 * lane + 1] = rv.y;
    __syncthreads();
#pragma unroll
    for (int jj = 0; jj < 2; ++jj) {
        int j = lane + jj * 64;
        float a = bf1[j];
        for (int k = 0; k < 128; ++k) a += rowb[w][k] * Wf1[k * 128 + j];
        tb[w][j] = fmaxf(a, 0.f);
    }
    __syncthreads();
    if (lane < 6) {
        float a = bf2v[lane];
        for (int k = 0; k < 128; ++k) a += tb[w][k] * Wf2[k * 6 + lane];
        out[g * 6 + lane] = 1.f / (1.f + __expf(-a));
    }
}

extern "C" void kernel_launch(void* const* d_in, const int* in_sizes, int n_in,
                              void* d_out, int out_size, void* d_ws, size_t ws_size,
                              hipStream_t stream) {
    const u32* x = (const u32*)d_in[0];
    const int* ei = (const int*)d_in[1];
    const int* src = ei;
    const int* dst = ei + N_EDGES;
    const int* batch = (const int*)d_in[2];
    float* out = (float*)d_out;

    char* ws = (char*)d_ws;
    int* deg = (int*)(ws + OFF_DEG);
    u16* bucket = (u16*)(ws + OFF_BUCKET);
    u32* XB = (u32*)(ws + OFF_XB);          // bf16 x; reused as h2
    u32* HSUM = (u32*)(ws + OFF_HSUM);
    u32* H1 = (u32*)(ws + OFF_H1);
    float* pooled = (float*)(ws + OFF_POOL);
    int* gstart = (int*)(ws + OFF_GS);
    int* gend = (int*)(ws + OFF_GE);
    u16* Wt = (u16*)(ws + OFF_WT);
    float* bc = (float*)(ws + OFF_BC);
    float* Wf1c = (float*)(ws + OFF_WF1);
    float* bf1c = (float*)(ws + OFF_BF1);
    float* Wf2c = (float*)(ws + OFF_WF2);
    float* bf2c = (float*)(ws + OFF_BF2);

    hipMemsetAsync(deg, 0, (size_t)N_NODES * DEGS * 4, stream);
    hipMemsetAsync(gstart, 0x7F, NG * 4, stream);
    hipMemsetAsync(gend, 0, NG * 4, stream);

    prep_params<<<326, 256, 0, stream>>>(ws,
        d_in[3], d_in[5], d_in[7], d_in[9],      // W1a, W1b, W2a, W2b
        d_in[4], d_in[6], d_in[8], d_in[10],     // b1a, b1b, b2a, b2b
        d_in[11], d_in[12], d_in[13], d_in[14]); // Wf1, bf1, Wf2, bf2
    cvt_x<<<(N_NODES * CHW) / 256, 256, 0, stream>>>(x, XB);
    fill_buckets<<<(N_EDGES + 255) / 256, 256, 0, stream>>>(src, dst, deg, bucket);
    graph_bounds<<<(N_NODES + 255) / 256, 256, 0, stream>>>(batch, gstart, gend);

    // layer 1: XB -> HSUM -> H1
    agg_kernel<<<(N_NODES + 3) / 4, 256, 0, stream>>>(XB, deg, bucket, HSUM);
    mlp_kernel<<<(N_NODES + 63) / 64, 256, 0, stream>>>((const u16*)HSUM, Wt, bc,
                                                        Wt + 16384, bc + 128, (u16*)H1, N_NODES);
    // layer 2: H1 -> HSUM -> XB (reused as h2)
    agg_kernel<<<(N_NODES + 3) / 4, 256, 0, stream>>>(H1, deg, bucket, HSUM);
    mlp_kernel<<<(N_NODES + 63) / 64, 256, 0, stream>>>((const u16*)HSUM, Wt + 32768, bc + 256,
                                                        Wt + 49152, bc + 384, (u16*)XB, N_NODES);
    // pool + head
    pool_kernel<<<(NG + 3) / 4, 256, 0, stream>>>(XB, gstart, gend, pooled);
    final_kernel<<<NG / 4, 256, 0, stream>>>(pooled, Wf1c, bf1c, Wf2c, bf2c, out);
}

// Round 11
// 338.821 us; speedup vs baseline: 1.8422x; 1.2430x over previous
//
#include <hip/hip_runtime.h>

typedef unsigned short u16;
typedef unsigned int u32;

#define N_NODES 50000
#define N_EDGES 1600000
#define CH 128
#define CHW 64          // u32 words per packed-bf16 row
#define NG 512
#define CAP 128         // bucket capacity per node (Poisson(32): P(>=128) ~ 1e-43)
#define PAD 136         // LDS row stride in bf16 elems (272B: 16B-aligned, bank-spread)
#define NBINS 196       // ceil(50000/256)
#define BINCAP 12288    // slots per bin (expect ~8192, max ~8650)
#define ECHUNK 6250     // edges per workgroup in edge_scatter (256 WGs exact)

typedef __bf16 bf16x8 __attribute__((ext_vector_type(8)));
typedef float f32x4 __attribute__((ext_vector_type(4)));

// ---- workspace byte offsets (total ~54.9 MB) ----
#define OFF_DEG 0ull              // 200,000 B (plain, no padding)
#define OFF_BUCKET 200192ull      // u16 bucket, 12,800,000 B
#define OFF_XB 13000192ull        // 12.8 MB packed-bf16 x; reused as h2
#define OFF_HSUM 25800192ull      // 12.8 MB; binned edges (9.6 MB) overlap here pre-agg
#define OFF_H1 38600192ull        // 12.8 MB
#define OFF_POOL 51400192ull      // 262,144 B
#define OFF_GS 51662336ull        // 2,048 B
#define OFF_GE 51664384ull        // 2,048 B
#define OFF_WT 51666432ull        // 4 x 32,768 B bf16 transposed weights [n][k]
#define OFF_BC 51797504ull        // 4 x 512 B fp32 biases
#define OFF_WF1 51799552ull       // 65,536 B fp32
#define OFF_BF1 51865088ull       // 512 B
#define OFF_WF2 51865600ull       // 3,072 B
#define OFF_BF2 51868672ull       // 32 B
#define OFF_BCUR 51868928ull      // 1,024 B bin cursors

__device__ __forceinline__ float bflo(u32 v) { return __builtin_bit_cast(float, v << 16); }
__device__ __forceinline__ float bfhi(u32 v) { return __builtin_bit_cast(float, v & 0xffff0000u); }
__device__ __forceinline__ float bf2f(u16 v) { return __builtin_bit_cast(float, ((u32)v) << 16); }
__device__ __forceinline__ u16 f2bf(float f) {
    u32 x = __builtin_bit_cast(u32, f);
    x += 0x7fffu + ((x >> 16) & 1u);   // RNE
    return (u16)(x >> 16);
}
__device__ __forceinline__ u32 pack2(float a, float b) {
    return (u32)f2bf(a) | ((u32)f2bf(b) << 16);
}
// wave-ballot probe: true if the 64 sampled u32 words look like packed bf16 pairs
__device__ __forceinline__ bool probe_bf16(u32 w0) {
    u32 ex = (w0 >> 7) & 0xFFu;
    bool ok = ((w0 & 0x7FFFu) == 0u) || (ex >= 0x70u && ex <= 0x8Fu);
    return __popcll(__ballot(ok)) >= 48;
}
__device__ __forceinline__ float loadf(const void* p, int i, bool isbf) {
    return isbf ? bf2f(((const u16*)p)[i]) : ((const float*)p)[i];
}

// ---------------- one-time param canonicalization ----------------
__global__ __launch_bounds__(256) void prep_params(char* ws,
                                                   const void* W0, const void* W1,
                                                   const void* W2, const void* W3,
                                                   const void* b0, const void* b1,
                                                   const void* b2, const void* b3,
                                                   const void* Wf1, const void* bf1,
                                                   const void* Wf2, const void* bf2) {
    int lane = threadIdx.x & 63;
    bool isbf = probe_bf16(((const u32*)W0)[lane]);
    int idx = blockIdx.x * 256 + threadIdx.x;
    u16* Wt = (u16*)(ws + OFF_WT);
    float* bc = (float*)(ws + OFF_BC);
    float* Wf1c = (float*)(ws + OFF_WF1);
    float* bf1c = (float*)(ws + OFF_BF1);
    float* Wf2c = (float*)(ws + OFF_WF2);
    float* bf2c = (float*)(ws + OFF_BF2);
    if (idx < 65536) {                       // Wt[j][n*128+k] = W[j][k*128+n], bf16
        int j = idx >> 14, r = idx & 16383;
        int n = r >> 7, k = r & 127;
        const void* src = (j == 0) ? W0 : (j == 1) ? W1 : (j == 2) ? W2 : W3;
        float v = loadf(src, k * 128 + n, isbf);
        Wt[idx] = f2bf(v);
    } else if (idx < 66048) {
        int r = idx - 65536, j = r >> 7, c = r & 127;
        const void* src = (j == 0) ? b0 : (j == 1) ? b1 : (j == 2) ? b2 : b3;
        bc[r] = loadf(src, c, isbf);
    } else if (idx < 82432) {
        Wf1c[idx - 66048] = loadf(Wf1, idx - 66048, isbf);
    } else if (idx < 82560) {
        bf1c[idx - 82432] = loadf(bf1, idx - 82432, isbf);
    } else if (idx < 83328) {
        Wf2c[idx - 82560] = loadf(Wf2, idx - 82560, isbf);
    } else if (idx < 83334) {
        bf2c[idx - 83328] = loadf(bf2, idx - 83328, isbf);
    }
}

// ---------------- x -> packed bf16 (once) ----------------
__global__ __launch_bounds__(256) void cvt_x(const u32* __restrict__ x, u32* __restrict__ xb) {
    int lane = threadIdx.x & 63;
    bool isbf = probe_bf16(x[lane]);
    int i = blockIdx.x * 256 + threadIdx.x;
    if (i >= N_NODES * CHW) return;
    if (isbf) {
        xb[i] = x[i];
    } else {
        float2 v = ((const float2*)x)[i];
        xb[i] = pack2(v.x, v.y);
    }
}

// ---------------- edge binning by dst>>8: 50K global atomics instead of 1.6M ----------------
__global__ __launch_bounds__(256) void edge_scatter(const int* __restrict__ ei,
                                                    int* __restrict__ binCursor,
                                                    u32* __restrict__ binned) {
    __shared__ u32 lhist[256];
    __shared__ u32 lbase[256];
    __shared__ u32 lcur[256];
    int tid = threadIdx.x, wg = blockIdx.x;
    int lane = tid & 63;
    u32 hiw = ((const u32*)ei)[2 * lane + 1];        // int64 => high words all 0
    bool i64 = __popcll(__ballot(hiw == 0u)) >= 48;
    int e0 = wg * ECHUNK;
    lhist[tid] = 0; lcur[tid] = 0;
    __syncthreads();
    for (int e = e0 + tid; e < e0 + ECHUNK; e += 256) {
        int d = i64 ? ei[2 * N_EDGES + 2 * e] : ei[N_EDGES + e];
        atomicAdd(&lhist[d >> 8], 1u);
    }
    __syncthreads();
    u32 c = lhist[tid];
    if (c) lbase[tid] = (u32)atomicAdd(&binCursor[tid], (int)c);
    __syncthreads();
    for (int e = e0 + tid; e < e0 + ECHUNK; e += 256) {
        int s, d;
        if (i64) { s = ei[2 * e]; d = ei[2 * N_EDGES + 2 * e]; }
        else     { s = ei[e];     d = ei[N_EDGES + e]; }
        int b = d >> 8;
        u32 p = atomicAdd(&lcur[b], 1u);
        binned[(size_t)b * BINCAP + lbase[b] + p] = ((u32)d << 16) | (u32)s;
    }
}

// ---------------- bucket build from binned edges: LDS atomics, hot 16KB window ----------------
__global__ __launch_bounds__(256) void fill_from_binned(const int* __restrict__ binCursor,
                                                        const u32* __restrict__ binned,
                                                        int* __restrict__ deg,
                                                        u16* __restrict__ bucket) {
    __shared__ u32 ldeg[256];
    int tid = threadIdx.x, b = blockIdx.x;
    int cnt = binCursor[b];
    ldeg[tid] = 0;
    __syncthreads();
    const u32* bp = binned + (size_t)b * BINCAP;
    for (int i = tid; i < cnt; i += 256) {
        u32 w = bp[i];
        u32 dl = (w >> 16) & 255u;
        u32 pos = atomicAdd(&ldeg[dl], 1u);
        if (pos < CAP) bucket[(size_t)(w >> 16) * CAP + pos] = (u16)(w & 0xFFFFu);
    }
    __syncthreads();
    int node = b * 256 + tid;
    if (node < N_NODES) deg[node] = (int)ldeg[tid];
}

// ---------------- aggregation: out[n] = h[n] + sum h[src], packed-bf16 in/out ----------------
__global__ __launch_bounds__(256) void agg_kernel(const u32* __restrict__ h,
                                                  const int* __restrict__ deg,
                                                  const u16* __restrict__ bucket,
                                                  u32* __restrict__ out) {
    int w = threadIdx.x >> 6, lane = threadIdx.x & 63;
    int node = blockIdx.x * 4 + w;
    if (node >= N_NODES) return;
    u32 self = h[(size_t)node * CHW + lane];
    float ax = bflo(self), ay = bfhi(self);
    int d = deg[node];
    d = d > CAP ? CAP : d;
    const u16* bk = bucket + (size_t)node * CAP;
    const u32* bkw = (const u32*)bk;            // 2 ids per word
    int j = 0;
    for (; j + 8 <= d; j += 8) {                // 8 gathers in flight
        u32 w0 = bkw[(j >> 1) + 0], w1 = bkw[(j >> 1) + 1];
        u32 w2 = bkw[(j >> 1) + 2], w3 = bkw[(j >> 1) + 3];
        u32 v0 = h[(size_t)(w0 & 0xFFFFu) * CHW + lane];
        u32 v1 = h[(size_t)(w0 >> 16) * CHW + lane];
        u32 v2 = h[(size_t)(w1 & 0xFFFFu) * CHW + lane];
        u32 v3 = h[(size_t)(w1 >> 16) * CHW + lane];
        u32 v4 = h[(size_t)(w2 & 0xFFFFu) * CHW + lane];
        u32 v5 = h[(size_t)(w2 >> 16) * CHW + lane];
        u32 v6 = h[(size_t)(w3 & 0xFFFFu) * CHW + lane];
        u32 v7 = h[(size_t)(w3 >> 16) * CHW + lane];
        ax += bflo(v0) + bflo(v1) + bflo(v2) + bflo(v3)
            + bflo(v4) + bflo(v5) + bflo(v6) + bflo(v7);
        ay += bfhi(v0) + bfhi(v1) + bfhi(v2) + bfhi(v3)
            + bfhi(v4) + bfhi(v5) + bfhi(v6) + bfhi(v7);
    }
    for (; j < d; ++j) {
        u32 v = h[(size_t)bk[j] * CHW + lane];
        ax += bflo(v);
        ay += bfhi(v);
    }
    out[(size_t)node * CHW + lane] = pack2(ax, ay);
}

// ---------------- fused 2-layer MLP: out = relu(relu(in@Wa+ba)@Wb+bb), bf16 MFMA ----------------
__global__ __launch_bounds__(256) void mlp_kernel(const u16* __restrict__ in,
                                                  const u16* __restrict__ Wta,
                                                  const float* __restrict__ ba,
                                                  const u16* __restrict__ Wtb,
                                                  const float* __restrict__ bb,
                                                  u16* __restrict__ out,
                                                  int nrows) {
    __shared__ __align__(16) u16 Wlds[128 * PAD];  // [n][k]
    __shared__ __align__(16) u16 tlds[64 * PAD];   // per-wave 16-row staging [r][k]
    const int tid = threadIdx.x;
    const int w = tid >> 6;
    const int lane = tid & 63;
    const int n16 = lane & 15;
    const int quad = lane >> 4;
    const int row0 = blockIdx.x * 64 + w * 16;
    const bool active = row0 < nrows;

    {   // stage Wa: 2048 x 16B copies, 8 per thread
        const uint4* wsrc = (const uint4*)Wta;
#pragma unroll
        for (int it = 0; it < 8; ++it) {
            int idx = tid + it * 256;
            int n = idx >> 4, c = idx & 15;
            *(uint4*)&Wlds[n * PAD + c * 8] = wsrc[idx];
        }
    }
    __syncthreads();

    f32x4 acc[8];
    bf16x8 afrag[4];
    if (active) {
        const u16* rowp = in + (size_t)(row0 + n16) * CH + quad * 8;
#pragma unroll
        for (int ks = 0; ks < 4; ++ks)
            afrag[ks] = *(const bf16x8*)(rowp + ks * 32);
#pragma unroll
        for (int ct = 0; ct < 8; ++ct) {
            f32x4 a = {0.f, 0.f, 0.f, 0.f};
#pragma unroll
            for (int ks = 0; ks < 4; ++ks) {
                bf16x8 b = *(const bf16x8*)&Wlds[(u32)(ct * 16 + n16) * PAD + ks * 32 + quad * 8];
                a = __builtin_amdgcn_mfma_f32_16x16x32_bf16(afrag[ks], b, a, 0, 0, 0);
            }
            acc[ct] = a;
        }
#pragma unroll
        for (int ct = 0; ct < 8; ++ct) {
            float bv = ba[ct * 16 + n16];
#pragma unroll
            for (int r = 0; r < 4; ++r) {
                float v = fmaxf(acc[ct][r] + bv, 0.f);
                tlds[(w * 16 + quad * 4 + r) * PAD + ct * 16 + n16] = f2bf(v);
            }
        }
    }
    __syncthreads();
    {   // stage Wb
        const uint4* wsrc = (const uint4*)Wtb;
#pragma unroll
        for (int it = 0; it < 8; ++it) {
            int idx = tid + it * 256;
            int n = idx >> 4, c = idx & 15;
            *(uint4*)&Wlds[n * PAD + c * 8] = wsrc[idx];
        }
    }
    __syncthreads();

    if (active) {
#pragma unroll
        for (int ks = 0; ks < 4; ++ks)
            afrag[ks] = *(const bf16x8*)&tlds[(u32)(w * 16 + n16) * PAD + ks * 32 + quad * 8];
#pragma unroll
        for (int ct = 0; ct < 8; ++ct) {
            f32x4 a = {0.f, 0.f, 0.f, 0.f};
#pragma unroll
            for (int ks = 0; ks < 4; ++ks) {
                bf16x8 b = *(const bf16x8*)&Wlds[(u32)(ct * 16 + n16) * PAD + ks * 32 + quad * 8];
                a = __builtin_amdgcn_mfma_f32_16x16x32_bf16(afrag[ks], b, a, 0, 0, 0);
            }
            acc[ct] = a;
        }
#pragma unroll
        for (int ct = 0; ct < 8; ++ct) {
            float bv = bb[ct * 16 + n16];
#pragma unroll
            for (int r = 0; r < 4; ++r) {
                float v = fmaxf(acc[ct][r] + bv, 0.f);
                tlds[(w * 16 + quad * 4 + r) * PAD + ct * 16 + n16] = f2bf(v);
            }
        }
        u32* outw = (u32*)out;
        for (int r = 0; r < 16; ++r) {
            u32 v = *(const u32*)&tlds[(w * 16 + r) * PAD + lane * 2];
            outw[(size_t)(row0 + r) * CHW + lane] = v;
        }
    }
}

// ---------------- per-graph node ranges (batch is sorted) ----------------
__global__ __launch_bounds__(256) void graph_bounds(const int* __restrict__ batch,
                                                    int* __restrict__ gstart,
                                                    int* __restrict__ gend) {
    int lane = threadIdx.x & 63;
    u32 hiw = ((const u32*)batch)[2 * (12500 + lane) + 1];   // mid-array: ids nonzero if int32
    bool i64 = __popcll(__ballot(hiw == 0u)) >= 48;
    int i = blockIdx.x * 256 + threadIdx.x;
    if (i >= N_NODES) return;
    int g = i64 ? batch[2 * i] : batch[i];
    atomicMin(&gstart[g], i);
    atomicMax(&gend[g], i + 1);
}

// ---------------- mean pool: one wave per graph, 4-deep ILP ----------------
__global__ __launch_bounds__(256) void pool_kernel(const u32* __restrict__ h,
                                                   const int* __restrict__ gstart,
                                                   const int* __restrict__ gend,
                                                   float* __restrict__ pooled) {
    int w = threadIdx.x >> 6, lane = threadIdx.x & 63;
    int g = blockIdx.x * 4 + w;
    if (g >= NG) return;
    int s = gstart[g], e = gend[g];
    float ax = 0.f, ay = 0.f;
    if (s < e) {
        int i = s;
        for (; i + 4 <= e; i += 4) {
            u32 v0 = h[(size_t)(i + 0) * CHW + lane];
            u32 v1 = h[(size_t)(i + 1) * CHW + lane];
            u32 v2 = h[(size_t)(i + 2) * CHW + lane];
            u32 v3 = h[(size_t)(i + 3) * CHW + lane];
            ax += bflo(v0) + bflo(v1) + bflo(v2) + bflo(v3);
            ay += bfhi(v0) + bfhi(v1) + bfhi(v2) + bfhi(v3);
        }
        for (; i < e; ++i) {
            u32 v = h[(size_t)i * CHW + lane];
            ax += bflo(v);
            ay += bfhi(v);
        }
    }
    float inv = 1.f / (float)((s < e) ? (e - s) : 1);
    ((float2*)pooled)[(size_t)g * CHW + lane] = make_float2(ax * inv, ay * inv);
}

// ---------------- head: sigmoid(relu(pooled@Wf1+bf1)@Wf2+bf2), fp32, fp32 out ----------------
__global__ __launch_bounds__(256) void final_kernel(const float* __restrict__ pooled,
                                                    const float* __restrict__ Wf1,
                                                    const float* __restrict__ bf1,
                                                    const float* __restrict__ Wf2,
                                                    const float* __restrict__ bf2v,
                                                    float* __restrict__ out) {
    __shared__ float rowb[4][128];
    __shared__ float tb[4][128];
    int w = threadIdx.x >> 6, lane = threadIdx.x & 63;
    int g = blockIdx.x * 4 + w;  // grid exact: 128 * 4 = 512
    float2 rv = ((const float2*)pooled)[(size_t)g * CHW + lane];
    rowb[w][2 * lane] = rv.x;
    rowb[w][2 * lane + 1] = rv.y;
    __syncthreads();
#pragma unroll
    for (int jj = 0; jj < 2; ++jj) {
        int j = lane + jj * 64;
        float a = bf1[j];
        for (int k = 0; k < 128; ++k) a += rowb[w][k] * Wf1[k * 128 + j];
        tb[w][j] = fmaxf(a, 0.f);
    }
    __syncthreads();
    if (lane < 6) {
        float a = bf2v[lane];
        for (int k = 0; k < 128; ++k) a += tb[w][k] * Wf2[k * 6 + lane];
        out[g * 6 + lane] = 1.f / (1.f + __expf(-a));
    }
}

extern "C" void kernel_launch(void* const* d_in, const int* in_sizes, int n_in,
                              void* d_out, int out_size, void* d_ws, size_t ws_size,
                              hipStream_t stream) {
    const u32* x = (const u32*)d_in[0];
    const int* ei = (const int*)d_in[1];
    const int* batch = (const int*)d_in[2];
    float* out = (float*)d_out;

    char* ws = (char*)d_ws;
    int* deg = (int*)(ws + OFF_DEG);
    u16* bucket = (u16*)(ws + OFF_BUCKET);
    u32* XB = (u32*)(ws + OFF_XB);          // bf16 x; reused as h2
    u32* HSUM = (u32*)(ws + OFF_HSUM);      // also binned-edge staging pre-agg
    u32* H1 = (u32*)(ws + OFF_H1);
    float* pooled = (float*)(ws + OFF_POOL);
    int* gstart = (int*)(ws + OFF_GS);
    int* gend = (int*)(ws + OFF_GE);
    u16* Wt = (u16*)(ws + OFF_WT);
    float* bc = (float*)(ws + OFF_BC);
    float* Wf1c = (float*)(ws + OFF_WF1);
    float* bf1c = (float*)(ws + OFF_BF1);
    float* Wf2c = (float*)(ws + OFF_WF2);
    float* bf2c = (float*)(ws + OFF_BF2);
    int* binCursor = (int*)(ws + OFF_BCUR);
    u32* binned = HSUM;

    hipMemsetAsync(binCursor, 0, 1024, stream);
    hipMemsetAsync(gstart, 0x7F, NG * 4, stream);
    hipMemsetAsync(gend, 0, NG * 4, stream);

    prep_params<<<326, 256, 0, stream>>>(ws,
        d_in[3], d_in[5], d_in[7], d_in[9],      // W1a, W1b, W2a, W2b
        d_in[4], d_in[6], d_in[8], d_in[10],     // b1a, b1b, b2a, b2b
        d_in[11], d_in[12], d_in[13], d_in[14]); // Wf1, bf1, Wf2, bf2
    cvt_x<<<(N_NODES * CHW) / 256, 256, 0, stream>>>(x, XB);
    edge_scatter<<<256, 256, 0, stream>>>(ei, binCursor, binned);
    fill_from_binned<<<NBINS, 256, 0, stream>>>(binCursor, binned, deg, bucket);
    graph_bounds<<<(N_NODES + 255) / 256, 256, 0, stream>>>(batch, gstart, gend);

    // layer 1: XB -> HSUM -> H1   (binned consumed; HSUM safely overwritten)
    agg_kernel<<<(N_NODES + 3) / 4, 256, 0, stream>>>(XB, deg, bucket, HSUM);
    mlp_kernel<<<(N_NODES + 63) / 64, 256, 0, stream>>>((const u16*)HSUM, Wt, bc,
                                                        Wt + 16384, bc + 128, (u16*)H1, N_NODES);
    // layer 2: H1 -> HSUM -> XB (reused as h2)
    agg_kernel<<<(N_NODES + 3) / 4, 256, 0, stream>>>(H1, deg, bucket, HSUM);
    mlp_kernel<<<(N_NODES + 63) / 64, 256, 0, stream>>>((const u16*)HSUM, Wt + 32768, bc + 256,
                                                        Wt + 49152, bc + 384, (u16*)XB, N_NODES);
    // pool + head
    pool_kernel<<<(NG + 3) / 4, 256, 0, stream>>>(XB, gstart, gend, pooled);
    final_kernel<<<NG / 4, 256, 0, stream>>>(pooled, Wf1c, bf1c, Wf2c, bf2c, out);
}

// Round 12
// 329.861 us; speedup vs baseline: 1.8922x; 1.0272x over previous
//
#include <hip/hip_runtime.h>

typedef unsigned short u16;
typedef unsigned int u32;

#define N_NODES 50000
#define N_EDGES 1600000
#define CH 128
#define CHW 64          // u32 words per packed-bf16 row
#define NG 512
#define CAP 128         // bucket capacity per node (Poisson(32): P(>=128) ~ 1e-43)
#define PAD 136         // LDS row stride in bf16 elems (272B: 16B-aligned, bank-spread)
#define NBINS 196       // ceil(50000/256)
#define BINCAP 12288    // slots per bin (expect ~8192, max ~8650)
#define NSCAT 512       // edge_scatter workgroups
#define ECHUNK 3125     // edges per workgroup (512*3125 = 1.6M exact)

typedef __bf16 bf16x8 __attribute__((ext_vector_type(8)));
typedef float f32x4 __attribute__((ext_vector_type(4)));

// ---- workspace byte offsets (total ~54.9 MB) ----
#define OFF_DEG 0ull              // 200,000 B
#define OFF_BUCKET 200192ull      // u16 bucket, 12,800,000 B
#define OFF_XB 13000192ull        // 12.8 MB packed-bf16 x; reused as h2
#define OFF_HSUM 25800192ull      // 12.8 MB; binned edges (9.6 MB) overlap here pre-agg
#define OFF_H1 38600192ull        // 12.8 MB
#define OFF_POOL 51400192ull      // 262,144 B
#define OFF_GS 51662336ull        // 2,048 B
#define OFF_GE 51664384ull        // 2,048 B
#define OFF_WT 51666432ull        // 4 x 32,768 B bf16 transposed weights [n][k]
#define OFF_BC 51797504ull        // 4 x 512 B fp32 biases
#define OFF_WF1 51799552ull       // 65,536 B fp32
#define OFF_BF1 51865088ull       // 512 B
#define OFF_WF2 51865600ull       // 3,072 B
#define OFF_BF2 51868672ull       // 32 B
#define OFF_BCUR 51868928ull      // 1,024 B bin cursors

__device__ __forceinline__ float bflo(u32 v) { return __builtin_bit_cast(float, v << 16); }
__device__ __forceinline__ float bfhi(u32 v) { return __builtin_bit_cast(float, v & 0xffff0000u); }
__device__ __forceinline__ float bf2f(u16 v) { return __builtin_bit_cast(float, ((u32)v) << 16); }
__device__ __forceinline__ u16 f2bf(float f) {
    u32 x = __builtin_bit_cast(u32, f);
    x += 0x7fffu + ((x >> 16) & 1u);   // RNE
    return (u16)(x >> 16);
}
__device__ __forceinline__ u32 pack2(float a, float b) {
    return (u32)f2bf(a) | ((u32)f2bf(b) << 16);
}
__device__ __forceinline__ bool probe_bf16(u32 w0) {
    u32 ex = (w0 >> 7) & 0xFFu;
    bool ok = ((w0 & 0x7FFFu) == 0u) || (ex >= 0x70u && ex <= 0x8Fu);
    return __popcll(__ballot(ok)) >= 48;
}
__device__ __forceinline__ float loadf(const void* p, int i, bool isbf) {
    return isbf ? bf2f(((const u16*)p)[i]) : ((const float*)p)[i];
}

// ---------------- one-time param canonicalization ----------------
__global__ __launch_bounds__(256) void prep_params(char* ws,
                                                   const void* W0, const void* W1,
                                                   const void* W2, const void* W3,
                                                   const void* b0, const void* b1,
                                                   const void* b2, const void* b3,
                                                   const void* Wf1, const void* bf1,
                                                   const void* Wf2, const void* bf2) {
    int lane = threadIdx.x & 63;
    bool isbf = probe_bf16(((const u32*)W0)[lane]);
    int idx = blockIdx.x * 256 + threadIdx.x;
    u16* Wt = (u16*)(ws + OFF_WT);
    float* bc = (float*)(ws + OFF_BC);
    float* Wf1c = (float*)(ws + OFF_WF1);
    float* bf1c = (float*)(ws + OFF_BF1);
    float* Wf2c = (float*)(ws + OFF_WF2);
    float* bf2c = (float*)(ws + OFF_BF2);
    if (idx < 65536) {                       // Wt[j][n*128+k] = W[j][k*128+n], bf16
        int j = idx >> 14, r = idx & 16383;
        int n = r >> 7, k = r & 127;
        const void* src = (j == 0) ? W0 : (j == 1) ? W1 : (j == 2) ? W2 : W3;
        float v = loadf(src, k * 128 + n, isbf);
        Wt[idx] = f2bf(v);
    } else if (idx < 66048) {
        int r = idx - 65536, j = r >> 7, c = r & 127;
        const void* src = (j == 0) ? b0 : (j == 1) ? b1 : (j == 2) ? b2 : b3;
        bc[r] = loadf(src, c, isbf);
    } else if (idx < 82432) {
        Wf1c[idx - 66048] = loadf(Wf1, idx - 66048, isbf);
    } else if (idx < 82560) {
        bf1c[idx - 82432] = loadf(bf1, idx - 82432, isbf);
    } else if (idx < 83328) {
        Wf2c[idx - 82560] = loadf(Wf2, idx - 82560, isbf);
    } else if (idx < 83334) {
        bf2c[idx - 83328] = loadf(bf2, idx - 83328, isbf);
    }
}

// ---------------- x -> packed bf16 (once) ----------------
__global__ __launch_bounds__(256) void cvt_x(const u32* __restrict__ x, u32* __restrict__ xb) {
    int lane = threadIdx.x & 63;
    bool isbf = probe_bf16(x[lane]);
    int i = blockIdx.x * 256 + threadIdx.x;
    if (i >= N_NODES * CHW) return;
    if (isbf) {
        xb[i] = x[i];
    } else {
        float2 v = ((const float2*)x)[i];
        xb[i] = pack2(v.x, v.y);
    }
}

// ---------------- edge binning by dst>>8 ----------------
__global__ __launch_bounds__(256) void edge_scatter(const int* __restrict__ ei,
                                                    int* __restrict__ binCursor,
                                                    u32* __restrict__ binned) {
    __shared__ u32 lhist[256];
    __shared__ u32 lbase[256];
    __shared__ u32 lcur[256];
    int tid = threadIdx.x, wg = blockIdx.x;
    int lane = tid & 63;
    u32 hiw = ((const u32*)ei)[2 * lane + 1];        // int64 => high words all 0
    bool i64 = __popcll(__ballot(hiw == 0u)) >= 48;
    int e0 = wg * ECHUNK;
    lhist[tid] = 0; lcur[tid] = 0;
    __syncthreads();
    for (int e = e0 + tid; e < e0 + ECHUNK; e += 256) {
        int d = i64 ? ei[2 * N_EDGES + 2 * e] : ei[N_EDGES + e];
        atomicAdd(&lhist[d >> 8], 1u);
    }
    __syncthreads();
    u32 c = lhist[tid];
    if (c) lbase[tid] = (u32)atomicAdd(&binCursor[tid], (int)c);
    __syncthreads();
    for (int e = e0 + tid; e < e0 + ECHUNK; e += 256) {
        int s, d;
        if (i64) { s = ei[2 * e]; d = ei[2 * N_EDGES + 2 * e]; }
        else     { s = ei[e];     d = ei[N_EDGES + e]; }
        int b = d >> 8;
        u32 p = atomicAdd(&lcur[b], 1u);
        binned[(size_t)b * BINCAP + lbase[b] + p] = ((u32)d << 16) | (u32)s;
    }
}

// ---------------- bucket build from binned edges ----------------
__global__ __launch_bounds__(256) void fill_from_binned(const int* __restrict__ binCursor,
                                                        const u32* __restrict__ binned,
                                                        int* __restrict__ deg,
                                                        u16* __restrict__ bucket) {
    __shared__ u32 ldeg[256];
    int tid = threadIdx.x, b = blockIdx.x;
    int cnt = binCursor[b];
    ldeg[tid] = 0;
    __syncthreads();
    const u32* bp = binned + (size_t)b * BINCAP;
    for (int i = tid; i < cnt; i += 256) {
        u32 w = bp[i];
        u32 dl = (w >> 16) & 255u;
        u32 pos = atomicAdd(&ldeg[dl], 1u);
        if (pos < CAP) bucket[(size_t)(w >> 16) * CAP + pos] = (u16)(w & 0xFFFFu);
    }
    __syncthreads();
    int node = b * 256 + tid;
    if (node < N_NODES) deg[node] = (int)ldeg[tid];
}

// ---------------- aggregation v2: uint4 gathers, 4 rows per load instruction ----------------
// lane = 16*sub + q; sub in [0,4) handles every 4th edge; q covers 16B of the row.
__global__ __launch_bounds__(256) void agg_kernel(const u32* __restrict__ h,
                                                  const int* __restrict__ deg,
                                                  const u16* __restrict__ bucket,
                                                  u32* __restrict__ out) {
    int w = threadIdx.x >> 6, lane = threadIdx.x & 63;
    int node = blockIdx.x * 4 + w;
    if (node >= N_NODES) return;
    int sub = lane >> 4, q = lane & 15;
    const uint4* h4 = (const uint4*)h;
    float acc[8];
    {   // self row, counted once (sub 0 only)
        uint4 sv = make_uint4(0u, 0u, 0u, 0u);
        if (sub == 0) sv = h4[(size_t)node * 16 + q];
        acc[0] = bflo(sv.x); acc[1] = bfhi(sv.x);
        acc[2] = bflo(sv.y); acc[3] = bfhi(sv.y);
        acc[4] = bflo(sv.z); acc[5] = bfhi(sv.z);
        acc[6] = bflo(sv.w); acc[7] = bfhi(sv.w);
    }
    int d = deg[node];
    d = d > CAP ? CAP : d;
    const u32* bkw = (const u32*)(bucket + (size_t)node * CAP);
    const u32 sh = (u32)(sub & 1) * 16u;
    const int widx = sub >> 1;
    int j = 0;
    for (; j + 16 <= d; j += 16) {           // 16 edges: 4 independent 4-row gathers in flight
        int base = j >> 1;
        u32 wd0 = bkw[base + widx];
        u32 wd1 = bkw[base + 2 + widx];
        u32 wd2 = bkw[base + 4 + widx];
        u32 wd3 = bkw[base + 6 + widx];
        uint4 v0 = h4[(size_t)((wd0 >> sh) & 0xFFFFu) * 16 + q];
        uint4 v1 = h4[(size_t)((wd1 >> sh) & 0xFFFFu) * 16 + q];
        uint4 v2 = h4[(size_t)((wd2 >> sh) & 0xFFFFu) * 16 + q];
        uint4 v3 = h4[(size_t)((wd3 >> sh) & 0xFFFFu) * 16 + q];
        acc[0] += bflo(v0.x) + bflo(v1.x) + bflo(v2.x) + bflo(v3.x);
        acc[1] += bfhi(v0.x) + bfhi(v1.x) + bfhi(v2.x) + bfhi(v3.x);
        acc[2] += bflo(v0.y) + bflo(v1.y) + bflo(v2.y) + bflo(v3.y);
        acc[3] += bfhi(v0.y) + bfhi(v1.y) + bfhi(v2.y) + bfhi(v3.y);
        acc[4] += bflo(v0.z) + bflo(v1.z) + bflo(v2.z) + bflo(v3.z);
        acc[5] += bfhi(v0.z) + bfhi(v1.z) + bfhi(v2.z) + bfhi(v3.z);
        acc[6] += bflo(v0.w) + bflo(v1.w) + bflo(v2.w) + bflo(v3.w);
        acc[7] += bfhi(v0.w) + bfhi(v1.w) + bfhi(v2.w) + bfhi(v3.w);
    }
    for (; j + 4 <= d; j += 4) {             // 4-edge groups
        u32 wd = bkw[(j >> 1) + widx];
        uint4 v = h4[(size_t)((wd >> sh) & 0xFFFFu) * 16 + q];
        acc[0] += bflo(v.x); acc[1] += bfhi(v.x);
        acc[2] += bflo(v.y); acc[3] += bfhi(v.y);
        acc[4] += bflo(v.z); acc[5] += bfhi(v.z);
        acc[6] += bflo(v.w); acc[7] += bfhi(v.w);
    }
    if (j + sub < d) {                       // tail (<4 edges), predicated per sub
        int e = j + sub;
        u32 wd = bkw[e >> 1];
        u32 id = (wd >> ((u32)(e & 1) * 16u)) & 0xFFFFu;
        uint4 v = h4[(size_t)id * 16 + q];
        acc[0] += bflo(v.x); acc[1] += bfhi(v.x);
        acc[2] += bflo(v.y); acc[3] += bfhi(v.y);
        acc[4] += bflo(v.z); acc[5] += bfhi(v.z);
        acc[6] += bflo(v.w); acc[7] += bfhi(v.w);
    }
#pragma unroll
    for (int c = 0; c < 8; ++c) {            // butterfly across the 4 sub-groups
        acc[c] += __shfl_xor(acc[c], 16, 64);
        acc[c] += __shfl_xor(acc[c], 32, 64);
    }
    if (sub == 0) {                          // 16 lanes x 16B = one contiguous 256B row
        uint4 o;
        o.x = pack2(acc[0], acc[1]);
        o.y = pack2(acc[2], acc[3]);
        o.z = pack2(acc[4], acc[5]);
        o.w = pack2(acc[6], acc[7]);
        ((uint4*)out)[(size_t)node * 16 + q] = o;
    }
}

// ---------------- fused 2-layer MLP: out = relu(relu(in@Wa+ba)@Wb+bb), bf16 MFMA ----------------
__global__ __launch_bounds__(256) void mlp_kernel(const u16* __restrict__ in,
                                                  const u16* __restrict__ Wta,
                                                  const float* __restrict__ ba,
                                                  const u16* __restrict__ Wtb,
                                                  const float* __restrict__ bb,
                                                  u16* __restrict__ out,
                                                  int nrows) {
    __shared__ __align__(16) u16 Wlds[128 * PAD];  // [n][k]
    __shared__ __align__(16) u16 tlds[64 * PAD];   // per-wave 16-row staging [r][k]
    const int tid = threadIdx.x;
    const int w = tid >> 6;
    const int lane = tid & 63;
    const int n16 = lane & 15;
    const int quad = lane >> 4;
    const int row0 = blockIdx.x * 64 + w * 16;
    const bool active = row0 < nrows;

    {   // stage Wa: 2048 x 16B copies, 8 per thread
        const uint4* wsrc = (const uint4*)Wta;
#pragma unroll
        for (int it = 0; it < 8; ++it) {
            int idx = tid + it * 256;
            int n = idx >> 4, c = idx & 15;
            *(uint4*)&Wlds[n * PAD + c * 8] = wsrc[idx];
        }
    }
    __syncthreads();

    f32x4 acc[8];
    bf16x8 afrag[4];
    if (active) {
        const u16* rowp = in + (size_t)(row0 + n16) * CH + quad * 8;
#pragma unroll
        for (int ks = 0; ks < 4; ++ks)
            afrag[ks] = *(const bf16x8*)(rowp + ks * 32);
#pragma unroll
        for (int ct = 0; ct < 8; ++ct) {
            f32x4 a = {0.f, 0.f, 0.f, 0.f};
#pragma unroll
            for (int ks = 0; ks < 4; ++ks) {
                bf16x8 b = *(const bf16x8*)&Wlds[(u32)(ct * 16 + n16) * PAD + ks * 32 + quad * 8];
                a = __builtin_amdgcn_mfma_f32_16x16x32_bf16(afrag[ks], b, a, 0, 0, 0);
            }
            acc[ct] = a;
        }
#pragma unroll
        for (int ct = 0; ct < 8; ++ct) {
            float bv = ba[ct * 16 + n16];
#pragma unroll
            for (int r = 0; r < 4; ++r) {
                float v = fmaxf(acc[ct][r] + bv, 0.f);
                tlds[(w * 16 + quad * 4 + r) * PAD + ct * 16 + n16] = f2bf(v);
            }
        }
    }
    __syncthreads();
    {   // stage Wb
        const uint4* wsrc = (const uint4*)Wtb;
#pragma unroll
        for (int it = 0; it < 8; ++it) {
            int idx = tid + it * 256;
            int n = idx >> 4, c = idx & 15;
            *(uint4*)&Wlds[n * PAD + c * 8] = wsrc[idx];
        }
    }
    __syncthreads();

    if (active) {
#pragma unroll
        for (int ks = 0; ks < 4; ++ks)
            afrag[ks] = *(const bf16x8*)&tlds[(u32)(w * 16 + n16) * PAD + ks * 32 + quad * 8];
#pragma unroll
        for (int ct = 0; ct < 8; ++ct) {
            f32x4 a = {0.f, 0.f, 0.f, 0.f};
#pragma unroll
            for (int ks = 0; ks < 4; ++ks) {
                bf16x8 b = *(const bf16x8*)&Wlds[(u32)(ct * 16 + n16) * PAD + ks * 32 + quad * 8];
                a = __builtin_amdgcn_mfma_f32_16x16x32_bf16(afrag[ks], b, a, 0, 0, 0);
            }
            acc[ct] = a;
        }
#pragma unroll
        for (int ct = 0; ct < 8; ++ct) {
            float bv = bb[ct * 16 + n16];
#pragma unroll
            for (int r = 0; r < 4; ++r) {
                float v = fmaxf(acc[ct][r] + bv, 0.f);
                tlds[(w * 16 + quad * 4 + r) * PAD + ct * 16 + n16] = f2bf(v);
            }
        }
        u32* outw = (u32*)out;
        for (int r = 0; r < 16; ++r) {
            u32 v = *(const u32*)&tlds[(w * 16 + r) * PAD + lane * 2];
            outw[(size_t)(row0 + r) * CHW + lane] = v;
        }
    }
}

// ---------------- per-graph node ranges (batch is sorted) ----------------
__global__ __launch_bounds__(256) void graph_bounds(const int* __restrict__ batch,
                                                    int* __restrict__ gstart,
                                                    int* __restrict__ gend) {
    int lane = threadIdx.x & 63;
    u32 hiw = ((const u32*)batch)[2 * (12500 + lane) + 1];   // mid-array: ids nonzero if int32
    bool i64 = __popcll(__ballot(hiw == 0u)) >= 48;
    int i = blockIdx.x * 256 + threadIdx.x;
    if (i >= N_NODES) return;
    int g = i64 ? batch[2 * i] : batch[i];
    atomicMin(&gstart[g], i);
    atomicMax(&gend[g], i + 1);
}

// ---------------- mean pool: one wave per graph, 4-deep ILP ----------------
__global__ __launch_bounds__(256) void pool_kernel(const u32* __restrict__ h,
                                                   const int* __restrict__ gstart,
                                                   const int* __restrict__ gend,
                                                   float* __restrict__ pooled) {
    int w = threadIdx.x >> 6, lane = threadIdx.x & 63;
    int g = blockIdx.x * 4 + w;
    if (g >= NG) return;
    int s = gstart[g], e = gend[g];
    float ax = 0.f, ay = 0.f;
    if (s < e) {
        int i = s;
        for (; i + 4 <= e; i += 4) {
            u32 v0 = h[(size_t)(i + 0) * CHW + lane];
            u32 v1 = h[(size_t)(i + 1) * CHW + lane];
            u32 v2 = h[(size_t)(i + 2) * CHW + lane];
            u32 v3 = h[(size_t)(i + 3) * CHW + lane];
            ax += bflo(v0) + bflo(v1) + bflo(v2) + bflo(v3);
            ay += bfhi(v0) + bfhi(v1) + bfhi(v2) + bfhi(v3);
        }
        for (; i < e; ++i) {
            u32 v = h[(size_t)i * CHW + lane];
            ax += bflo(v);
            ay += bfhi(v);
        }
    }
    float inv = 1.f / (float)((s < e) ? (e - s) : 1);
    ((float2*)pooled)[(size_t)g * CHW + lane] = make_float2(ax * inv, ay * inv);
}

// ---------------- head: sigmoid(relu(pooled@Wf1+bf1)@Wf2+bf2), fp32, fp32 out ----------------
__global__ __launch_bounds__(256) void final_kernel(const float* __restrict__ pooled,
                                                    const float* __restrict__ Wf1,
                                                    const float* __restrict__ bf1,
                                                    const float* __restrict__ Wf2,
                                                    const float* __restrict__ bf2v,
                                                    float* __restrict__ out) {
    __shared__ float rowb[4][128];
    __shared__ float tb[4][128];
    int w = threadIdx.x >> 6, lane = threadIdx.x & 63;
    int g = blockIdx.x * 4 + w;  // grid exact: 128 * 4 = 512
    float2 rv = ((const float2*)pooled)[(size_t)g * CHW + lane];
    rowb[w][2 * lane] = rv.x;
    rowb[w][2 * lane + 1] = rv.y;
    __syncthreads();
#pragma unroll
    for (int jj = 0; jj < 2; ++jj) {
        int j = lane + jj * 64;
        float a = bf1[j];
        for (int k = 0; k < 128; ++k) a += rowb[w][k] * Wf1[k * 128 + j];
        tb[w][j] = fmaxf(a, 0.f);
    }
    __syncthreads();
    if (lane < 6) {
        float a = bf2v[lane];
        for (int k = 0; k < 128; ++k) a += tb[w][k] * Wf2[k * 6 + lane];
        out[g * 6 + lane] = 1.f / (1.f + __expf(-a));
    }
}

extern "C" void kernel_launch(void* const* d_in, const int* in_sizes, int n_in,
                              void* d_out, int out_size, void* d_ws, size_t ws_size,
                              hipStream_t stream) {
    const u32* x = (const u32*)d_in[0];
    const int* ei = (const int*)d_in[1];
    const int* batch = (const int*)d_in[2];
    float* out = (float*)d_out;

    char* ws = (char*)d_ws;
    int* deg = (int*)(ws + OFF_DEG);
    u16* bucket = (u16*)(ws + OFF_BUCKET);
    u32* XB = (u32*)(ws + OFF_XB);
    u32* HSUM = (u32*)(ws + OFF_HSUM);
    u32* H1 = (u32*)(ws + OFF_H1);
    float* pooled = (float*)(ws + OFF_POOL);
    int* gstart = (int*)(ws + OFF_GS);
    int* gend = (int*)(ws + OFF_GE);
    u16* Wt = (u16*)(ws + OFF_WT);
    float* bc = (float*)(ws + OFF_BC);
    float* Wf1c = (float*)(ws + OFF_WF1);
    float* bf1c = (float*)(ws + OFF_BF1);
    float* Wf2c = (float*)(ws + OFF_WF2);
    float* bf2c = (float*)(ws + OFF_BF2);
    int* binCursor = (int*)(ws + OFF_BCUR);
    u32* binned = HSUM;

    hipMemsetAsync(binCursor, 0, 1024, stream);
    hipMemsetAsync(gstart, 0x7F, NG * 4, stream);
    hipMemsetAsync(gend, 0, NG * 4, stream);

    prep_params<<<326, 256, 0, stream>>>(ws,
        d_in[3], d_in[5], d_in[7], d_in[9],      // W1a, W1b, W2a, W2b
        d_in[4], d_in[6], d_in[8], d_in[10],     // b1a, b1b, b2a, b2b
        d_in[11], d_in[12], d_in[13], d_in[14]); // Wf1, bf1, Wf2, bf2
    cvt_x<<<(N_NODES * CHW) / 256, 256, 0, stream>>>(x, XB);
    edge_scatter<<<NSCAT, 256, 0, stream>>>(ei, binCursor, binned);
    fill_from_binned<<<NBINS, 256, 0, stream>>>(binCursor, binned, deg, bucket);
    graph_bounds<<<(N_NODES + 255) / 256, 256, 0, stream>>>(batch, gstart, gend);

    // layer 1: XB -> HSUM -> H1   (binned consumed; HSUM safely overwritten)
    agg_kernel<<<(N_NODES + 3) / 4, 256, 0, stream>>>(XB, deg, bucket, HSUM);
    mlp_kernel<<<(N_NODES + 63) / 64, 256, 0, stream>>>((const u16*)HSUM, Wt, bc,
                                                        Wt + 16384, bc + 128, (u16*)H1, N_NODES);
    // layer 2: H1 -> HSUM -> XB (reused as h2)
    agg_kernel<<<(N_NODES + 3) / 4, 256, 0, stream>>>(H1, deg, bucket, HSUM);
    mlp_kernel<<<(N_NODES + 63) / 64, 256, 0, stream>>>((const u16*)HSUM, Wt + 32768, bc + 256,
                                                        Wt + 49152, bc + 384, (u16*)XB, N_NODES);
    // pool + head
    pool_kernel<<<(NG + 3) / 4, 256, 0, stream>>>(XB, gstart, gend, pooled);
    final_kernel<<<NG / 4, 256, 0, stream>>>(pooled, Wf1c, bf1c, Wf2c, bf2c, out);
}